// Round 5
// baseline (632.231 us; speedup 1.0000x reference)
//
#include <hip/hip_runtime.h>
#include <hip/hip_bf16.h>

#define NNODES 32768
#define DEG 16

__device__ __forceinline__ float sigmoidf_(float x) { return 1.f / (1.f + __expf(-x)); }
__device__ __forceinline__ float tanhf_(float x) { return 1.f - 2.f / (__expf(2.f * x) + 1.f); }

// ---------------------------------------------------------------------------
// Fused triple FC (same input, three weight sets): out_z = in @ W_z + b_z.
// blockIdx.z in {0,1,2} selects (W,b,out). W row-major [FI][FO].
// ---------------------------------------------------------------------------
template <int FI, int FO>
__global__ __launch_bounds__(256) void fc3_kernel(
    const float* __restrict__ in,
    const float* __restrict__ W0, const float* __restrict__ B0, float* __restrict__ O0,
    const float* __restrict__ W1, const float* __restrict__ B1, float* __restrict__ O1,
    const float* __restrict__ W2, const float* __restrict__ B2, float* __restrict__ O2) {
  constexpr int ROWS = 32;
  constexpr int FOT = (FO < 64) ? FO : 64;
  constexpr int NJ = FOT;
  constexpr int RSL = 256 / NJ;
  constexpr int R = ROWS / RSL;
  constexpr int PFI = (FI + 4) & ~3;
  __shared__ float w_s[FI * FOT];
  __shared__ float in_s[ROWS * PFI];
  __shared__ float b_s[FOT];
  const float* W = (blockIdx.z == 0) ? W0 : (blockIdx.z == 1) ? W1 : W2;
  const float* bias = (blockIdx.z == 0) ? B0 : (blockIdx.z == 1) ? B1 : B2;
  float* out = (blockIdx.z == 0) ? O0 : (blockIdx.z == 1) ? O1 : O2;
  const int t = threadIdx.x;
  const int rowBase = blockIdx.x * ROWS;
  const int colBase = blockIdx.y * FOT;
  for (int idx = t; idx < FI * FOT; idx += 256) {
    int k = idx / FOT, jj = idx - k * FOT;
    w_s[idx] = W[(size_t)k * FO + colBase + jj];
  }
  if (t < FOT) b_s[t] = bias[colBase + t];
  for (int idx = t; idx < ROWS * FI; idx += 256) {
    int r = idx / FI, k = idx - r * FI;
    in_s[r * PFI + k] = in[(size_t)(rowBase + r) * FI + k];
  }
  __syncthreads();
  const int jj = t % NJ;
  const int rslot = t / NJ;
  float acc[R];
#pragma unroll
  for (int r = 0; r < R; r++) acc[r] = b_s[jj];
  constexpr int K4 = FI / 4;
#pragma unroll
  for (int k4 = 0; k4 < K4; k4++) {
    float wv0 = w_s[(4 * k4 + 0) * FOT + jj];
    float wv1 = w_s[(4 * k4 + 1) * FOT + jj];
    float wv2 = w_s[(4 * k4 + 2) * FOT + jj];
    float wv3 = w_s[(4 * k4 + 3) * FOT + jj];
#pragma unroll
    for (int r = 0; r < R; r++) {
      float4 ip = *(const float4*)&in_s[(rslot * R + r) * PFI + 4 * k4];
      acc[r] += ip.x * wv0 + ip.y * wv1 + ip.z * wv2 + ip.w * wv3;
    }
  }
#pragma unroll
  for (int k = 4 * K4; k < FI; k++) {
    float wv = w_s[k * FOT + jj];
#pragma unroll
    for (int r = 0; r < R; r++) acc[r] += in_s[(rslot * R + r) * PFI + k] * wv;
  }
#pragma unroll
  for (int r = 0; r < R; r++)
    out[(size_t)(rowBase + rslot * R + r) * FO + colBase + jj] = acc[r];
}

// ---------------------------------------------------------------------------
// Single FC for XW2 = x1 @ wih.T + b  (W given [FO][FI], used transposed)
// ---------------------------------------------------------------------------
template <int FI, int FO>
__global__ __launch_bounds__(256) void fct_kernel(const float* __restrict__ in,
                                                  const float* __restrict__ W,
                                                  const float* __restrict__ bias,
                                                  float* __restrict__ out) {
  constexpr int ROWS = 32;
  constexpr int FOT = (FO < 64) ? FO : 64;
  constexpr int NJ = FOT;
  constexpr int RSL = 256 / NJ;
  constexpr int R = ROWS / RSL;
  constexpr int PFI = (FI + 4) & ~3;
  __shared__ float w_s[FI * FOT];
  __shared__ float in_s[ROWS * PFI];
  __shared__ float b_s[FOT];
  const int t = threadIdx.x;
  const int rowBase = blockIdx.x * ROWS;
  const int colBase = blockIdx.y * FOT;
  for (int idx = t; idx < FI * FOT; idx += 256) {
    int k = idx / FOT, jj = idx - k * FOT;
    w_s[idx] = W[(size_t)(colBase + jj) * FI + k];
  }
  if (t < FOT) b_s[t] = bias[colBase + t];
  for (int idx = t; idx < ROWS * FI; idx += 256) {
    int r = idx / FI, k = idx - r * FI;
    in_s[r * PFI + k] = in[(size_t)(rowBase + r) * FI + k];
  }
  __syncthreads();
  const int jj = t % NJ;
  const int rslot = t / NJ;
  float acc[R];
#pragma unroll
  for (int r = 0; r < R; r++) acc[r] = b_s[jj];
  constexpr int K4 = FI / 4;
#pragma unroll
  for (int k4 = 0; k4 < K4; k4++) {
    float wv0 = w_s[(4 * k4 + 0) * FOT + jj];
    float wv1 = w_s[(4 * k4 + 1) * FOT + jj];
    float wv2 = w_s[(4 * k4 + 2) * FOT + jj];
    float wv3 = w_s[(4 * k4 + 3) * FOT + jj];
#pragma unroll
    for (int r = 0; r < R; r++) {
      float4 ip = *(const float4*)&in_s[(rslot * R + r) * PFI + 4 * k4];
      acc[r] += ip.x * wv0 + ip.y * wv1 + ip.z * wv2 + ip.w * wv3;
    }
  }
#pragma unroll
  for (int r = 0; r < R; r++)
    out[(size_t)(rowBase + rslot * R + r) * FO + colBase + jj] = acc[r];
}

// ---------------------------------------------------------------------------
// GATv2 attention + epilogue (unchanged).
// ---------------------------------------------------------------------------
template <int H, bool ELU>
__global__ __launch_bounds__(256) void gat_kernel(const float* __restrict__ fs,
                                                  const float* __restrict__ fd,
                                                  const float* __restrict__ lin,
                                                  const int* __restrict__ src,
                                                  const float* __restrict__ attn,
                                                  const float* __restrict__ bias,
                                                  float* __restrict__ out) {
  constexpr int F = H * 32;
  const int lane = threadIdx.x & 63;
  const int wave = threadIdx.x >> 6;
  const int G = lane >> 4, li = lane & 15;
  int node, f0;
  if (H == 4) {
    node = blockIdx.x * 4 + wave;
    f0 = 2 * lane;
  } else {
    node = blockIdx.x * 16 + wave * 4 + G;
    f0 = 2 * li;
  }
  const int srcv = src[(size_t)node * DEG + li];
  const float2 fdv = *(const float2*)&fd[(size_t)node * F + f0];
  const float a0 = attn[f0];
  const float a1 = attn[f0 + 1];
  float m = -1e30f, s = 0.f, acc0 = 0.f, acc1 = 0.f;
  int sd = __shfl(srcv, (lane & 48), 64);
  float2 fsv = *(const float2*)&fs[(size_t)sd * F + f0];
#pragma unroll
  for (int d = 0; d < DEG; d++) {
    float2 cur = fsv;
    if (d < DEG - 1) {
      int sn = __shfl(srcv, (lane & 48) | (d + 1), 64);
      fsv = *(const float2*)&fs[(size_t)sn * F + f0];
    }
    float e0 = cur.x + fdv.x; e0 = (e0 > 0.f) ? e0 : 0.2f * e0;
    float e1 = cur.y + fdv.y; e1 = (e1 > 0.f) ? e1 : 0.2f * e1;
    float p = e0 * a0 + e1 * a1;
    p += __shfl_xor(p, 1, 64);
    p += __shfl_xor(p, 2, 64);
    p += __shfl_xor(p, 4, 64);
    p += __shfl_xor(p, 8, 64);
    float nm = fmaxf(m, p);
    float ex = __expf(p - nm);
    float sc = __expf(m - nm);
    s = s * sc + ex;
    acc0 = acc0 * sc + ex * cur.x;
    acc1 = acc1 * sc + ex * cur.y;
    m = nm;
  }
  float inv = 1.f / s;
  float2 lv = *(const float2*)&lin[(size_t)node * F + f0];
  float o0 = acc0 * inv + lv.x + bias[f0];
  float o1 = acc1 * inv + lv.y + bias[f0 + 1];
  if (ELU) {
    o0 = (o0 > 0.f) ? o0 : __expf(o0) - 1.f;
    o1 = (o1 > 0.f) ? o1 : __expf(o1) - 1.f;
  }
  *(float2*)&out[(size_t)node * F + f0] = make_float2(o0, o1);
}

// ---------------------------------------------------------------------------
// SAGE-1 input projection: FW[n][20] = feat[n][5] @ wih.T + b   (thread/node)
// ---------------------------------------------------------------------------
__global__ __launch_bounds__(256) void fw1_kernel(const float* __restrict__ feat,
                                                  const float* __restrict__ wih,
                                                  const float* __restrict__ b,
                                                  float* __restrict__ out) {
  __shared__ float w_s[100];
  __shared__ float b_s[20];
  if (threadIdx.x < 100) w_s[threadIdx.x] = wih[threadIdx.x];
  if (threadIdx.x < 20) b_s[threadIdx.x] = b[threadIdx.x];
  __syncthreads();
  const int n = blockIdx.x * 256 + threadIdx.x;
  float f[5];
#pragma unroll
  for (int k = 0; k < 5; k++) f[k] = feat[(size_t)n * 5 + k];
#pragma unroll
  for (int j = 0; j < 20; j++) {
    float a = b_s[j];
#pragma unroll
    for (int k = 0; k < 5; k++) a += f[k] * w_s[j * 5 + k];
    out[(size_t)n * 20 + j] = a;
  }
}

// ---------------------------------------------------------------------------
// SAGE-1: LSTM (hidden=5, thread/node) + fused output projection (unchanged).
// ---------------------------------------------------------------------------
__global__ __attribute__((amdgpu_waves_per_eu(1, 4))) __launch_bounds__(256)
void lstm1s_kernel(const float* __restrict__ FW, const int* __restrict__ src,
                   const float* __restrict__ whh, const float* __restrict__ feat,
                   const float* __restrict__ wself, const float* __restrict__ wneigh,
                   const float* __restrict__ bias, float* __restrict__ x1out) {
  __shared__ float w_s[100];   // whh [20][5]
  __shared__ float ws_s[160];  // wself [5][32]
  __shared__ float wn_s[160];  // wneigh [5][32]
  __shared__ float b_s[32];
  if (threadIdx.x < 100) w_s[threadIdx.x] = whh[threadIdx.x];
  if (threadIdx.x < 160) {
    ws_s[threadIdx.x] = wself[threadIdx.x];
    wn_s[threadIdx.x] = wneigh[threadIdx.x];
  }
  if (threadIdx.x < 32) b_s[threadIdx.x] = bias[threadIdx.x];
  __syncthreads();
  const int n = blockIdx.x * 256 + threadIdx.x;
  const int* sp = src + (size_t)n * DEG;
  float f[5];
#pragma unroll
  for (int k = 0; k < 5; k++) f[k] = feat[(size_t)n * 5 + k];
  float h[5] = {0, 0, 0, 0, 0}, c[5] = {0, 0, 0, 0, 0};
  int sd = sp[0];
  float4 p0 = *(const float4*)&FW[(size_t)sd * 20 + 0];
  float4 p1 = *(const float4*)&FW[(size_t)sd * 20 + 4];
  float4 p2 = *(const float4*)&FW[(size_t)sd * 20 + 8];
  float4 p3 = *(const float4*)&FW[(size_t)sd * 20 + 12];
  float4 p4 = *(const float4*)&FW[(size_t)sd * 20 + 16];
  for (int d = 0; d < DEG; d++) {
    float g[20];
    g[0] = p0.x; g[1] = p0.y; g[2] = p0.z; g[3] = p0.w;
    g[4] = p1.x; g[5] = p1.y; g[6] = p1.z; g[7] = p1.w;
    g[8] = p2.x; g[9] = p2.y; g[10] = p2.z; g[11] = p2.w;
    g[12] = p3.x; g[13] = p3.y; g[14] = p3.z; g[15] = p3.w;
    g[16] = p4.x; g[17] = p4.y; g[18] = p4.z; g[19] = p4.w;
    if (d < DEG - 1) {
      int sn = sp[d + 1];
      p0 = *(const float4*)&FW[(size_t)sn * 20 + 0];
      p1 = *(const float4*)&FW[(size_t)sn * 20 + 4];
      p2 = *(const float4*)&FW[(size_t)sn * 20 + 8];
      p3 = *(const float4*)&FW[(size_t)sn * 20 + 12];
      p4 = *(const float4*)&FW[(size_t)sn * 20 + 16];
    }
#pragma unroll
    for (int j = 0; j < 20; j++) {
#pragma unroll
      for (int k = 0; k < 5; k++) g[j] += h[k] * w_s[j * 5 + k];
    }
#pragma unroll
    for (int k = 0; k < 5; k++) {
      float iv = sigmoidf_(g[k]);
      float fv = sigmoidf_(g[5 + k]);
      float gv = tanhf_(g[10 + k]);
      float ov = sigmoidf_(g[15 + k]);
      c[k] = fv * c[k] + iv * gv;
      h[k] = ov * tanhf_(c[k]);
    }
  }
#pragma unroll
  for (int j = 0; j < 32; j++) {
    float a = b_s[j];
#pragma unroll
    for (int k = 0; k < 5; k++) a += f[k] * ws_s[k * 32 + j] + h[k] * wn_s[k * 32 + j];
    x1out[(size_t)n * 32 + j] = fmaxf(a, 0.f);
  }
}

// ---------------------------------------------------------------------------
// SAGE-2 LSTM v2: TWO waves per node, 32 whh floats per lane.
// R4 post-mortem: 64 weights/lane can't be kept resident (RA spills toward
// the 64-reg/8-wave budget no matter what hints we give: VGPR_Count=60 across
// R2/R3/R4) and LDS-streaming whh is bytes-infeasible (16KB/node/step = 32
// MB/CU = ~109us). Fix: halve the per-lane footprint so the kernel FITS the
// 64-reg budget. Wave half 0 = gate rows 0..63 (i|f), half 1 = rows 64..127
// (g|o); lane owns row j = half*64+lane (32 weights + ~20 state ~= 52 regs).
// i/f/g/o recombine through act_lds with 2 barriers/step; h broadcast via
// same-address b128 reads (free). c,h owned by half-0 lanes<32.
// ---------------------------------------------------------------------------
__global__ __launch_bounds__(256)
void lstm2s_kernel(const float* __restrict__ XW, const int* __restrict__ src,
                   const float* __restrict__ whh, const float* __restrict__ x1,
                   const float* __restrict__ wself, const float* __restrict__ wneigh,
                   const float* __restrict__ bias, float* __restrict__ x2out) {
  __shared__ float sw_lds[2048];      // wself[1024] ++ wneigh[1024]
  __shared__ float act_lds[2][128];   // per node slot: i|f|g|o activations
  __shared__ float h_lds[2][36];
  __shared__ float x1_lds[2][32];
  const int t = threadIdx.x;
  const int lane = t & 63;
  const int wave = t >> 6;
  const int ns = wave >> 1;        // node slot within block
  const int half = wave & 1;       // gate-row half
  const int node = blockIdx.x * 2 + ns;
  const int j = half * 64 + lane;  // owned gate row 0..127
  for (int i = t; i < 1024; i += 256) {
    sw_lds[i] = wself[i];
    sw_lds[1024 + i] = wneigh[i];
  }
  float w[32];
#pragma unroll
  for (int k4 = 0; k4 < 8; k4++) {
    float4 a = *(const float4*)&whh[(size_t)j * 32 + 4 * k4];
    w[4 * k4 + 0] = a.x; w[4 * k4 + 1] = a.y;
    w[4 * k4 + 2] = a.z; w[4 * k4 + 3] = a.w;
  }
#pragma unroll
  for (int k = 0; k < 32; k++) asm volatile("" : "+v"(w[k]));  // no remat
  if (half == 0 && lane < 32) {
    h_lds[ns][lane] = 0.f;
    x1_lds[ns][lane] = x1[(size_t)node * 32 + lane];
  }
  __syncthreads();
  const int* sp = src + (size_t)node * DEG;
  int sd = sp[0];
  float xw = XW[(size_t)sd * 128 + j];
  float c = 0.f, h = 0.f;
#pragma unroll 1
  for (int d = 0; d < DEG; d++) {
    float g = xw;
#pragma unroll
    for (int k4 = 0; k4 < 8; k4++) {
      float4 h4 = *(const float4*)&h_lds[ns][4 * k4];  // broadcast
      g += h4.x * w[4 * k4 + 0] + h4.y * w[4 * k4 + 1] +
           h4.z * w[4 * k4 + 2] + h4.w * w[4 * k4 + 3];
    }
    if (d < DEG - 1) {
      int sn = sp[d + 1];
      xw = XW[(size_t)sn * 128 + j];  // prefetch across the barriers
    }
    float act;
    if (half == 0) act = sigmoidf_(g);                          // i | f
    else act = (lane < 32) ? tanhf_(g) : sigmoidf_(g);          // g | o
    act_lds[ns][j] = act;
    __syncthreads();
    if (half == 0 && lane < 32) {
      float iv = act_lds[ns][lane];
      float fv = act_lds[ns][32 + lane];
      float gv = act_lds[ns][64 + lane];
      float ov = act_lds[ns][96 + lane];
      c = fv * c + iv * gv;
      h = ov * tanhf_(c);
      h_lds[ns][lane] = h;
    }
    __syncthreads();
  }
  // fused SAGE-2 output: x2 = relu(x1 @ wself + hn @ wneigh + bias)
  if (half == 0 && lane < 32) {
    float a = bias[lane];
#pragma unroll
    for (int k = 0; k < 32; k++) {
      a += x1_lds[ns][k] * sw_lds[k * 32 + lane] +
           h_lds[ns][k] * sw_lds[1024 + k * 32 + lane];
    }
    x2out[(size_t)node * 32 + lane] = fmaxf(a, 0.f);
  }
}

// ---------------------------------------------------------------------------
// Final MLP: out = relu([gat,x2] @ f1 + b1) @ f2 + b2   (thread per node)
// ---------------------------------------------------------------------------
__global__ __attribute__((amdgpu_waves_per_eu(4, 4))) __launch_bounds__(256)
void final_kernel(const float* __restrict__ gat,
                  const float* __restrict__ x2,
                  const float* __restrict__ f1w,
                  const float* __restrict__ f1b,
                  const float* __restrict__ f2w,
                  const float* __restrict__ f2b,
                  float* __restrict__ out) {
  __shared__ float w1_s[64 * 16];
  __shared__ float b1_s[16];
  __shared__ float w2_s[16];
  for (int idx = threadIdx.x; idx < 1024; idx += 256) w1_s[idx] = f1w[idx];
  if (threadIdx.x < 16) {
    b1_s[threadIdx.x] = f1b[threadIdx.x];
    w2_s[threadIdx.x] = f2w[threadIdx.x];
  }
  __syncthreads();
  const int n = blockIdx.x * 256 + threadIdx.x;
  float z[64];
#pragma unroll
  for (int k = 0; k < 32; k += 4) {
    float4 a = *(const float4*)&gat[(size_t)n * 32 + k];
    z[k] = a.x; z[k + 1] = a.y; z[k + 2] = a.z; z[k + 3] = a.w;
    float4 b = *(const float4*)&x2[(size_t)n * 32 + k];
    z[32 + k] = b.x; z[32 + k + 1] = b.y; z[32 + k + 2] = b.z; z[32 + k + 3] = b.w;
  }
  float o = f2b[0];
#pragma unroll
  for (int j = 0; j < 16; j++) {
    float a = b1_s[j];
#pragma unroll
    for (int k = 0; k < 64; k++) a += z[k] * w1_s[k * 16 + j];
    o += fmaxf(a, 0.f) * w2_s[j];
  }
  out[n] = o;
}

extern "C" void kernel_launch(void* const* d_in, const int* in_sizes, int n_in,
                              void* d_out, int out_size, void* d_ws, size_t ws_size,
                              hipStream_t stream) {
  const int N = NNODES;
  const float* feat = (const float*)d_in[0];
  const int* src = (const int*)d_in[1];
  const float* g0_ws = (const float*)d_in[2];
  const float* g0_bs = (const float*)d_in[3];
  const float* g0_wd = (const float*)d_in[4];
  const float* g0_bd = (const float*)d_in[5];
  const float* g0_attn = (const float*)d_in[6];
  const float* g0_bias = (const float*)d_in[7];
  const float* l0_w = (const float*)d_in[8];
  const float* l0_b = (const float*)d_in[9];
  const float* g1_ws = (const float*)d_in[10];
  const float* g1_bs = (const float*)d_in[11];
  const float* g1_wd = (const float*)d_in[12];
  const float* g1_bd = (const float*)d_in[13];
  const float* g1_attn = (const float*)d_in[14];
  const float* g1_bias = (const float*)d_in[15];
  const float* l1_w = (const float*)d_in[16];
  const float* l1_b = (const float*)d_in[17];
  const float* g2_ws = (const float*)d_in[18];
  const float* g2_bs = (const float*)d_in[19];
  const float* g2_wd = (const float*)d_in[20];
  const float* g2_bd = (const float*)d_in[21];
  const float* g2_attn = (const float*)d_in[22];
  const float* g2_bias = (const float*)d_in[23];
  const float* l2_w = (const float*)d_in[24];
  const float* l2_b = (const float*)d_in[25];
  const float* s1_wih = (const float*)d_in[26];
  const float* s1_whh = (const float*)d_in[27];
  const float* s1_b = (const float*)d_in[28];
  const float* s1_wself = (const float*)d_in[29];
  const float* s1_wneigh = (const float*)d_in[30];
  const float* s1_bias = (const float*)d_in[31];
  const float* s2_wih = (const float*)d_in[32];
  const float* s2_whh = (const float*)d_in[33];
  const float* s2_b = (const float*)d_in[34];
  const float* s2_wself = (const float*)d_in[35];
  const float* s2_wneigh = (const float*)d_in[36];
  const float* s2_bias = (const float*)d_in[37];
  const float* f1_w = (const float*)d_in[38];
  const float* f1_b = (const float*)d_in[39];
  const float* f2_w = (const float*)d_in[40];
  const float* f2_b = (const float*)d_in[41];

  float* A = (float*)d_ws;                // N*128
  float* B = A + (size_t)N * 128;
  float* C = B + (size_t)N * 128;
  float* D = C + (size_t)N * 128;
  float* E = D + (size_t)N * 128;         // total 84 MB

  // ---- GAT layer 0 (fi=5, H=4): fs->A fd->B lin->C ----
  fc3_kernel<5, 128><<<dim3(N / 32, 2, 3), 256, 0, stream>>>(
      feat, g0_ws, g0_bs, A, g0_wd, g0_bd, B, l0_w, l0_b, C);
  gat_kernel<4, true><<<N / 4, 256, 0, stream>>>(A, B, C, src, g0_attn, g0_bias, D);  // D = h1

  // ---- GAT layer 1 (fi=128, H=4) ----
  fc3_kernel<128, 128><<<dim3(N / 32, 2, 3), 256, 0, stream>>>(
      D, g1_ws, g1_bs, A, g1_wd, g1_bd, B, l1_w, l1_b, C);
  gat_kernel<4, true><<<N / 4, 256, 0, stream>>>(A, B, C, src, g1_attn, g1_bias, E);  // E = h2

  // ---- GAT layer 2 (fi=128, H=1) ----
  fc3_kernel<128, 32><<<dim3(N / 32, 1, 3), 256, 0, stream>>>(
      E, g2_ws, g2_bs, A, g2_wd, g2_bd, B, l2_w, l2_b, C);
  gat_kernel<1, false><<<N / 16, 256, 0, stream>>>(A, B, C, src, g2_attn, g2_bias, D);  // D = gat [N,32]

  // ---- SAGE layer 1 ----
  fw1_kernel<<<N / 256, 256, 0, stream>>>(feat, s1_wih, s1_b, E);  // E = FW1 [N,20]
  lstm1s_kernel<<<N / 256, 256, 0, stream>>>(E, src, s1_whh, feat, s1_wself,
                                             s1_wneigh, s1_bias, C);  // C = x1 [N,32]

  // ---- SAGE layer 2 ----
  fct_kernel<32, 128><<<dim3(N / 32, 2), 256, 0, stream>>>(C, s2_wih, s2_b, A);  // A = XW2
  lstm2s_kernel<<<N / 2, 256, 0, stream>>>(A, src, s2_whh, C, s2_wself,
                                           s2_wneigh, s2_bias, B);  // B = x2 [N,32]

  // ---- Final MLP ----
  final_kernel<<<N / 256, 256, 0, stream>>>(D, B, f1_w, f1_b, f2_w, f2_b, (float*)d_out);
}

// Round 6
// 541.938 us; speedup vs baseline: 1.1666x; 1.1666x over previous
//
#include <hip/hip_runtime.h>
#include <hip/hip_bf16.h>

#define NNODES 32768
#define DEG 16

__device__ __forceinline__ float sigmoidf_(float x) { return 1.f / (1.f + __expf(-x)); }
__device__ __forceinline__ float tanhf_(float x) { return 1.f - 2.f / (__expf(2.f * x) + 1.f); }

// ---------------------------------------------------------------------------
// Fused triple FC (same input, three weight sets): out_z = in @ W_z + b_z.
// ---------------------------------------------------------------------------
template <int FI, int FO>
__global__ __launch_bounds__(256) void fc3_kernel(
    const float* __restrict__ in,
    const float* __restrict__ W0, const float* __restrict__ B0, float* __restrict__ O0,
    const float* __restrict__ W1, const float* __restrict__ B1, float* __restrict__ O1,
    const float* __restrict__ W2, const float* __restrict__ B2, float* __restrict__ O2) {
  constexpr int ROWS = 32;
  constexpr int FOT = (FO < 64) ? FO : 64;
  constexpr int NJ = FOT;
  constexpr int RSL = 256 / NJ;
  constexpr int R = ROWS / RSL;
  constexpr int PFI = (FI + 4) & ~3;
  __shared__ float w_s[FI * FOT];
  __shared__ float in_s[ROWS * PFI];
  __shared__ float b_s[FOT];
  const float* W = (blockIdx.z == 0) ? W0 : (blockIdx.z == 1) ? W1 : W2;
  const float* bias = (blockIdx.z == 0) ? B0 : (blockIdx.z == 1) ? B1 : B2;
  float* out = (blockIdx.z == 0) ? O0 : (blockIdx.z == 1) ? O1 : O2;
  const int t = threadIdx.x;
  const int rowBase = blockIdx.x * ROWS;
  const int colBase = blockIdx.y * FOT;
  for (int idx = t; idx < FI * FOT; idx += 256) {
    int k = idx / FOT, jj = idx - k * FOT;
    w_s[idx] = W[(size_t)k * FO + colBase + jj];
  }
  if (t < FOT) b_s[t] = bias[colBase + t];
  for (int idx = t; idx < ROWS * FI; idx += 256) {
    int r = idx / FI, k = idx - r * FI;
    in_s[r * PFI + k] = in[(size_t)(rowBase + r) * FI + k];
  }
  __syncthreads();
  const int jj = t % NJ;
  const int rslot = t / NJ;
  float acc[R];
#pragma unroll
  for (int r = 0; r < R; r++) acc[r] = b_s[jj];
  constexpr int K4 = FI / 4;
#pragma unroll
  for (int k4 = 0; k4 < K4; k4++) {
    float wv0 = w_s[(4 * k4 + 0) * FOT + jj];
    float wv1 = w_s[(4 * k4 + 1) * FOT + jj];
    float wv2 = w_s[(4 * k4 + 2) * FOT + jj];
    float wv3 = w_s[(4 * k4 + 3) * FOT + jj];
#pragma unroll
    for (int r = 0; r < R; r++) {
      float4 ip = *(const float4*)&in_s[(rslot * R + r) * PFI + 4 * k4];
      acc[r] += ip.x * wv0 + ip.y * wv1 + ip.z * wv2 + ip.w * wv3;
    }
  }
#pragma unroll
  for (int k = 4 * K4; k < FI; k++) {
    float wv = w_s[k * FOT + jj];
#pragma unroll
    for (int r = 0; r < R; r++) acc[r] += in_s[(rslot * R + r) * PFI + k] * wv;
  }
#pragma unroll
  for (int r = 0; r < R; r++)
    out[(size_t)(rowBase + rslot * R + r) * FO + colBase + jj] = acc[r];
}

// ---------------------------------------------------------------------------
// Single FC for XW2 = x1 @ wih.T + b  (W given [FO][FI], used transposed)
// ---------------------------------------------------------------------------
template <int FI, int FO>
__global__ __launch_bounds__(256) void fct_kernel(const float* __restrict__ in,
                                                  const float* __restrict__ W,
                                                  const float* __restrict__ bias,
                                                  float* __restrict__ out) {
  constexpr int ROWS = 32;
  constexpr int FOT = (FO < 64) ? FO : 64;
  constexpr int NJ = FOT;
  constexpr int RSL = 256 / NJ;
  constexpr int R = ROWS / RSL;
  constexpr int PFI = (FI + 4) & ~3;
  __shared__ float w_s[FI * FOT];
  __shared__ float in_s[ROWS * PFI];
  __shared__ float b_s[FOT];
  const int t = threadIdx.x;
  const int rowBase = blockIdx.x * ROWS;
  const int colBase = blockIdx.y * FOT;
  for (int idx = t; idx < FI * FOT; idx += 256) {
    int k = idx / FOT, jj = idx - k * FOT;
    w_s[idx] = W[(size_t)(colBase + jj) * FI + k];
  }
  if (t < FOT) b_s[t] = bias[colBase + t];
  for (int idx = t; idx < ROWS * FI; idx += 256) {
    int r = idx / FI, k = idx - r * FI;
    in_s[r * PFI + k] = in[(size_t)(rowBase + r) * FI + k];
  }
  __syncthreads();
  const int jj = t % NJ;
  const int rslot = t / NJ;
  float acc[R];
#pragma unroll
  for (int r = 0; r < R; r++) acc[r] = b_s[jj];
  constexpr int K4 = FI / 4;
#pragma unroll
  for (int k4 = 0; k4 < K4; k4++) {
    float wv0 = w_s[(4 * k4 + 0) * FOT + jj];
    float wv1 = w_s[(4 * k4 + 1) * FOT + jj];
    float wv2 = w_s[(4 * k4 + 2) * FOT + jj];
    float wv3 = w_s[(4 * k4 + 3) * FOT + jj];
#pragma unroll
    for (int r = 0; r < R; r++) {
      float4 ip = *(const float4*)&in_s[(rslot * R + r) * PFI + 4 * k4];
      acc[r] += ip.x * wv0 + ip.y * wv1 + ip.z * wv2 + ip.w * wv3;
    }
  }
#pragma unroll
  for (int r = 0; r < R; r++)
    out[(size_t)(rowBase + rslot * R + r) * FO + colBase + jj] = acc[r];
}

// ---------------------------------------------------------------------------
// GATv2 attention + epilogue (unchanged).
// ---------------------------------------------------------------------------
template <int H, bool ELU>
__global__ __launch_bounds__(256) void gat_kernel(const float* __restrict__ fs,
                                                  const float* __restrict__ fd,
                                                  const float* __restrict__ lin,
                                                  const int* __restrict__ src,
                                                  const float* __restrict__ attn,
                                                  const float* __restrict__ bias,
                                                  float* __restrict__ out) {
  constexpr int F = H * 32;
  const int lane = threadIdx.x & 63;
  const int wave = threadIdx.x >> 6;
  const int G = lane >> 4, li = lane & 15;
  int node, f0;
  if (H == 4) {
    node = blockIdx.x * 4 + wave;
    f0 = 2 * lane;
  } else {
    node = blockIdx.x * 16 + wave * 4 + G;
    f0 = 2 * li;
  }
  const int srcv = src[(size_t)node * DEG + li];
  const float2 fdv = *(const float2*)&fd[(size_t)node * F + f0];
  const float a0 = attn[f0];
  const float a1 = attn[f0 + 1];
  float m = -1e30f, s = 0.f, acc0 = 0.f, acc1 = 0.f;
  int sd = __shfl(srcv, (lane & 48), 64);
  float2 fsv = *(const float2*)&fs[(size_t)sd * F + f0];
#pragma unroll
  for (int d = 0; d < DEG; d++) {
    float2 cur = fsv;
    if (d < DEG - 1) {
      int sn = __shfl(srcv, (lane & 48) | (d + 1), 64);
      fsv = *(const float2*)&fs[(size_t)sn * F + f0];
    }
    float e0 = cur.x + fdv.x; e0 = (e0 > 0.f) ? e0 : 0.2f * e0;
    float e1 = cur.y + fdv.y; e1 = (e1 > 0.f) ? e1 : 0.2f * e1;
    float p = e0 * a0 + e1 * a1;
    p += __shfl_xor(p, 1, 64);
    p += __shfl_xor(p, 2, 64);
    p += __shfl_xor(p, 4, 64);
    p += __shfl_xor(p, 8, 64);
    float nm = fmaxf(m, p);
    float ex = __expf(p - nm);
    float sc = __expf(m - nm);
    s = s * sc + ex;
    acc0 = acc0 * sc + ex * cur.x;
    acc1 = acc1 * sc + ex * cur.y;
    m = nm;
  }
  float inv = 1.f / s;
  float2 lv = *(const float2*)&lin[(size_t)node * F + f0];
  float o0 = acc0 * inv + lv.x + bias[f0];
  float o1 = acc1 * inv + lv.y + bias[f0 + 1];
  if (ELU) {
    o0 = (o0 > 0.f) ? o0 : __expf(o0) - 1.f;
    o1 = (o1 > 0.f) ? o1 : __expf(o1) - 1.f;
  }
  *(float2*)&out[(size_t)node * F + f0] = make_float2(o0, o1);
}

// ---------------------------------------------------------------------------
// SAGE-1 input projection: FW[n][20] = feat[n][5] @ wih.T + b   (thread/node)
// ---------------------------------------------------------------------------
__global__ __launch_bounds__(256) void fw1_kernel(const float* __restrict__ feat,
                                                  const float* __restrict__ wih,
                                                  const float* __restrict__ b,
                                                  float* __restrict__ out) {
  __shared__ float w_s[100];
  __shared__ float b_s[20];
  if (threadIdx.x < 100) w_s[threadIdx.x] = wih[threadIdx.x];
  if (threadIdx.x < 20) b_s[threadIdx.x] = b[threadIdx.x];
  __syncthreads();
  const int n = blockIdx.x * 256 + threadIdx.x;
  float f[5];
#pragma unroll
  for (int k = 0; k < 5; k++) f[k] = feat[(size_t)n * 5 + k];
#pragma unroll
  for (int j = 0; j < 20; j++) {
    float a = b_s[j];
#pragma unroll
    for (int k = 0; k < 5; k++) a += f[k] * w_s[j * 5 + k];
    out[(size_t)n * 20 + j] = a;
  }
}

// ---------------------------------------------------------------------------
// SAGE-1: LSTM (hidden=5, thread/node) + fused output projection (unchanged).
// ---------------------------------------------------------------------------
__global__ __attribute__((amdgpu_waves_per_eu(1, 4))) __launch_bounds__(256)
void lstm1s_kernel(const float* __restrict__ FW, const int* __restrict__ src,
                   const float* __restrict__ whh, const float* __restrict__ feat,
                   const float* __restrict__ wself, const float* __restrict__ wneigh,
                   const float* __restrict__ bias, float* __restrict__ x1out) {
  __shared__ float w_s[100];   // whh [20][5]
  __shared__ float ws_s[160];  // wself [5][32]
  __shared__ float wn_s[160];  // wneigh [5][32]
  __shared__ float b_s[32];
  if (threadIdx.x < 100) w_s[threadIdx.x] = whh[threadIdx.x];
  if (threadIdx.x < 160) {
    ws_s[threadIdx.x] = wself[threadIdx.x];
    wn_s[threadIdx.x] = wneigh[threadIdx.x];
  }
  if (threadIdx.x < 32) b_s[threadIdx.x] = bias[threadIdx.x];
  __syncthreads();
  const int n = blockIdx.x * 256 + threadIdx.x;
  const int* sp = src + (size_t)n * DEG;
  float f[5];
#pragma unroll
  for (int k = 0; k < 5; k++) f[k] = feat[(size_t)n * 5 + k];
  float h[5] = {0, 0, 0, 0, 0}, c[5] = {0, 0, 0, 0, 0};
  int sd = sp[0];
  float4 p0 = *(const float4*)&FW[(size_t)sd * 20 + 0];
  float4 p1 = *(const float4*)&FW[(size_t)sd * 20 + 4];
  float4 p2 = *(const float4*)&FW[(size_t)sd * 20 + 8];
  float4 p3 = *(const float4*)&FW[(size_t)sd * 20 + 12];
  float4 p4 = *(const float4*)&FW[(size_t)sd * 20 + 16];
  for (int d = 0; d < DEG; d++) {
    float g[20];
    g[0] = p0.x; g[1] = p0.y; g[2] = p0.z; g[3] = p0.w;
    g[4] = p1.x; g[5] = p1.y; g[6] = p1.z; g[7] = p1.w;
    g[8] = p2.x; g[9] = p2.y; g[10] = p2.z; g[11] = p2.w;
    g[12] = p3.x; g[13] = p3.y; g[14] = p3.z; g[15] = p3.w;
    g[16] = p4.x; g[17] = p4.y; g[18] = p4.z; g[19] = p4.w;
    if (d < DEG - 1) {
      int sn = sp[d + 1];
      p0 = *(const float4*)&FW[(size_t)sn * 20 + 0];
      p1 = *(const float4*)&FW[(size_t)sn * 20 + 4];
      p2 = *(const float4*)&FW[(size_t)sn * 20 + 8];
      p3 = *(const float4*)&FW[(size_t)sn * 20 + 12];
      p4 = *(const float4*)&FW[(size_t)sn * 20 + 16];
    }
#pragma unroll
    for (int j = 0; j < 20; j++) {
#pragma unroll
      for (int k = 0; k < 5; k++) g[j] += h[k] * w_s[j * 5 + k];
    }
#pragma unroll
    for (int k = 0; k < 5; k++) {
      float iv = sigmoidf_(g[k]);
      float fv = sigmoidf_(g[5 + k]);
      float gv = tanhf_(g[10 + k]);
      float ov = sigmoidf_(g[15 + k]);
      c[k] = fv * c[k] + iv * gv;
      h[k] = ov * tanhf_(c[k]);
    }
  }
#pragma unroll
  for (int j = 0; j < 32; j++) {
    float a = b_s[j];
#pragma unroll
    for (int k = 0; k < 5; k++) a += f[k] * ws_s[k * 32 + j] + h[k] * wn_s[k * 32 + j];
    x1out[(size_t)n * 32 + j] = fmaxf(a, 0.f);
  }
}

// ---------------------------------------------------------------------------
// SAGE-2 LSTM v3: block = 128 threads = 2 waves = ONE node.
// R5 post-mortem: 32 w/lane fits the 64-reg budget (VGPR=48, no spill) but
// block=256 (2 nodes, 4 waves) lockstepped through 32 block-wide barriers ->
// only 2 independent streams/SIMD -> latency-bound (per-SIMD VALU ~18%).
// Fixes: (1) block=128: barrier scope halves, 4 independent blocks/SIMD;
// (2) ALL 16 xw values preloaded into regs at block start (1 float/lane/step,
// loads issued back-to-back, one exposed round-trip instead of 16 serial
// HBM-latency hits: XW table is 16.8MB vs 4MiB/XCD L2 -> gathers miss L2);
// asm fences keep both w[] and xw[] resident (R2 remat lesson).
// Gate rows: half0 lane = rows 0..63 (i|f), half1 = rows 64..127 (g|o).
// ---------------------------------------------------------------------------
__global__ __launch_bounds__(128)
void lstm2_kernel(const float* __restrict__ XW, const int* __restrict__ src,
                  const float* __restrict__ whh, float* __restrict__ hn_out) {
  __shared__ float h_lds[32];
  __shared__ float act_lds[128];
  const int t = threadIdx.x;       // 0..127
  const int lane = t & 63;
  const int half = t >> 6;         // wave within block
  const int node = blockIdx.x;
  const int j = half * 64 + lane;  // owned gate row 0..127
  float w[32];
#pragma unroll
  for (int k4 = 0; k4 < 8; k4++) {
    float4 a = *(const float4*)&whh[(size_t)j * 32 + 4 * k4];
    w[4 * k4 + 0] = a.x; w[4 * k4 + 1] = a.y;
    w[4 * k4 + 2] = a.z; w[4 * k4 + 3] = a.w;
  }
  // preload all DEG xw values (one float per lane per step)
  const int* sp = src + (size_t)node * DEG;
  float xw[DEG];
#pragma unroll
  for (int q = 0; q < DEG / 4; q++) {
    int4 iq = *(const int4*)&sp[4 * q];
    xw[4 * q + 0] = XW[(size_t)iq.x * 128 + j];
    xw[4 * q + 1] = XW[(size_t)iq.y * 128 + j];
    xw[4 * q + 2] = XW[(size_t)iq.z * 128 + j];
    xw[4 * q + 3] = XW[(size_t)iq.w * 128 + j];
  }
#pragma unroll
  for (int k = 0; k < 32; k++) asm volatile("" : "+v"(w[k]));
#pragma unroll
  for (int d = 0; d < DEG; d++) asm volatile("" : "+v"(xw[d]));
  if (t < 32) h_lds[t] = 0.f;
  __syncthreads();
  float c = 0.f, h = 0.f;
#pragma unroll
  for (int d = 0; d < DEG; d++) {
    float g = xw[d];
#pragma unroll
    for (int k4 = 0; k4 < 8; k4++) {
      float4 h4 = *(const float4*)&h_lds[4 * k4];  // same-address broadcast
      g += h4.x * w[4 * k4 + 0] + h4.y * w[4 * k4 + 1] +
           h4.z * w[4 * k4 + 2] + h4.w * w[4 * k4 + 3];
    }
    float act;
    if (half == 0) act = sigmoidf_(g);                   // i | f rows
    else act = (lane < 32) ? tanhf_(g) : sigmoidf_(g);   // g | o rows
    act_lds[j] = act;
    __syncthreads();
    if (t < 32) {
      float iv = act_lds[t];
      float fv = act_lds[32 + t];
      float gv = act_lds[64 + t];
      float ov = act_lds[96 + t];
      c = fv * c + iv * gv;
      h = ov * tanhf_(c);
      h_lds[t] = h;
    }
    __syncthreads();
  }
  if (t < 32) hn_out[(size_t)node * 32 + t] = h;
}

// ---------------------------------------------------------------------------
// SAGE output: out = relu(in @ wself + hn @ wneigh + bias), FO=32
// ---------------------------------------------------------------------------
template <int FI>
__global__ __launch_bounds__(256) void sage_out_kernel(const float* __restrict__ in,
                                                       const float* __restrict__ hn,
                                                       const float* __restrict__ wself,
                                                       const float* __restrict__ wneigh,
                                                       const float* __restrict__ bias,
                                                       float* __restrict__ out) {
  __shared__ float ws_s[FI * 32];
  __shared__ float wn_s[FI * 32];
  __shared__ float b_s[32];
  for (int idx = threadIdx.x; idx < FI * 32; idx += 256) {
    ws_s[idx] = wself[idx];
    wn_s[idx] = wneigh[idx];
  }
  if (threadIdx.x < 32) b_s[threadIdx.x] = bias[threadIdx.x];
  __syncthreads();
  const int n = blockIdx.x * 8 + (threadIdx.x >> 5);
  const int j = threadIdx.x & 31;
  float a = b_s[j];
#pragma unroll
  for (int k = 0; k < FI; k++) a += in[(size_t)n * FI + k] * ws_s[k * 32 + j];
#pragma unroll
  for (int k = 0; k < FI; k++) a += hn[(size_t)n * FI + k] * wn_s[k * 32 + j];
  out[(size_t)n * 32 + j] = fmaxf(a, 0.f);
}

// ---------------------------------------------------------------------------
// Final MLP: out = relu([gat,x2] @ f1 + b1) @ f2 + b2   (thread per node)
// ---------------------------------------------------------------------------
__global__ __attribute__((amdgpu_waves_per_eu(4, 4))) __launch_bounds__(256)
void final_kernel(const float* __restrict__ gat,
                  const float* __restrict__ x2,
                  const float* __restrict__ f1w,
                  const float* __restrict__ f1b,
                  const float* __restrict__ f2w,
                  const float* __restrict__ f2b,
                  float* __restrict__ out) {
  __shared__ float w1_s[64 * 16];
  __shared__ float b1_s[16];
  __shared__ float w2_s[16];
  for (int idx = threadIdx.x; idx < 1024; idx += 256) w1_s[idx] = f1w[idx];
  if (threadIdx.x < 16) {
    b1_s[threadIdx.x] = f1b[threadIdx.x];
    w2_s[threadIdx.x] = f2w[threadIdx.x];
  }
  __syncthreads();
  const int n = blockIdx.x * 256 + threadIdx.x;
  float z[64];
#pragma unroll
  for (int k = 0; k < 32; k += 4) {
    float4 a = *(const float4*)&gat[(size_t)n * 32 + k];
    z[k] = a.x; z[k + 1] = a.y; z[k + 2] = a.z; z[k + 3] = a.w;
    float4 b = *(const float4*)&x2[(size_t)n * 32 + k];
    z[32 + k] = b.x; z[32 + k + 1] = b.y; z[32 + k + 2] = b.z; z[32 + k + 3] = b.w;
  }
  float o = f2b[0];
#pragma unroll
  for (int j = 0; j < 16; j++) {
    float a = b1_s[j];
#pragma unroll
    for (int k = 0; k < 64; k++) a += z[k] * w1_s[k * 16 + j];
    o += fmaxf(a, 0.f) * w2_s[j];
  }
  out[n] = o;
}

extern "C" void kernel_launch(void* const* d_in, const int* in_sizes, int n_in,
                              void* d_out, int out_size, void* d_ws, size_t ws_size,
                              hipStream_t stream) {
  const int N = NNODES;
  const float* feat = (const float*)d_in[0];
  const int* src = (const int*)d_in[1];
  const float* g0_ws = (const float*)d_in[2];
  const float* g0_bs = (const float*)d_in[3];
  const float* g0_wd = (const float*)d_in[4];
  const float* g0_bd = (const float*)d_in[5];
  const float* g0_attn = (const float*)d_in[6];
  const float* g0_bias = (const float*)d_in[7];
  const float* l0_w = (const float*)d_in[8];
  const float* l0_b = (const float*)d_in[9];
  const float* g1_ws = (const float*)d_in[10];
  const float* g1_bs = (const float*)d_in[11];
  const float* g1_wd = (const float*)d_in[12];
  const float* g1_bd = (const float*)d_in[13];
  const float* g1_attn = (const float*)d_in[14];
  const float* g1_bias = (const float*)d_in[15];
  const float* l1_w = (const float*)d_in[16];
  const float* l1_b = (const float*)d_in[17];
  const float* g2_ws = (const float*)d_in[18];
  const float* g2_bs = (const float*)d_in[19];
  const float* g2_wd = (const float*)d_in[20];
  const float* g2_bd = (const float*)d_in[21];
  const float* g2_attn = (const float*)d_in[22];
  const float* g2_bias = (const float*)d_in[23];
  const float* l2_w = (const float*)d_in[24];
  const float* l2_b = (const float*)d_in[25];
  const float* s1_wih = (const float*)d_in[26];
  const float* s1_whh = (const float*)d_in[27];
  const float* s1_b = (const float*)d_in[28];
  const float* s1_wself = (const float*)d_in[29];
  const float* s1_wneigh = (const float*)d_in[30];
  const float* s1_bias = (const float*)d_in[31];
  const float* s2_wih = (const float*)d_in[32];
  const float* s2_whh = (const float*)d_in[33];
  const float* s2_b = (const float*)d_in[34];
  const float* s2_wself = (const float*)d_in[35];
  const float* s2_wneigh = (const float*)d_in[36];
  const float* s2_bias = (const float*)d_in[37];
  const float* f1_w = (const float*)d_in[38];
  const float* f1_b = (const float*)d_in[39];
  const float* f2_w = (const float*)d_in[40];
  const float* f2_b = (const float*)d_in[41];

  float* A = (float*)d_ws;                // N*128
  float* B = A + (size_t)N * 128;
  float* C = B + (size_t)N * 128;
  float* D = C + (size_t)N * 128;
  float* E = D + (size_t)N * 128;         // total 84 MB

  // ---- GAT layer 0 (fi=5, H=4): fs->A fd->B lin->C ----
  fc3_kernel<5, 128><<<dim3(N / 32, 2, 3), 256, 0, stream>>>(
      feat, g0_ws, g0_bs, A, g0_wd, g0_bd, B, l0_w, l0_b, C);
  gat_kernel<4, true><<<N / 4, 256, 0, stream>>>(A, B, C, src, g0_attn, g0_bias, D);  // D = h1

  // ---- GAT layer 1 (fi=128, H=4) ----
  fc3_kernel<128, 128><<<dim3(N / 32, 2, 3), 256, 0, stream>>>(
      D, g1_ws, g1_bs, A, g1_wd, g1_bd, B, l1_w, l1_b, C);
  gat_kernel<4, true><<<N / 4, 256, 0, stream>>>(A, B, C, src, g1_attn, g1_bias, E);  // E = h2

  // ---- GAT layer 2 (fi=128, H=1) ----
  fc3_kernel<128, 32><<<dim3(N / 32, 1, 3), 256, 0, stream>>>(
      E, g2_ws, g2_bs, A, g2_wd, g2_bd, B, l2_w, l2_b, C);
  gat_kernel<1, false><<<N / 16, 256, 0, stream>>>(A, B, C, src, g2_attn, g2_bias, D);  // D = gat [N,32]

  // ---- SAGE layer 1 ----
  fw1_kernel<<<N / 256, 256, 0, stream>>>(feat, s1_wih, s1_b, E);  // E = FW1 [N,20]
  lstm1s_kernel<<<N / 256, 256, 0, stream>>>(E, src, s1_whh, feat, s1_wself,
                                             s1_wneigh, s1_bias, C);  // C = x1 [N,32]

  // ---- SAGE layer 2 ----
  fct_kernel<32, 128><<<dim3(N / 32, 2), 256, 0, stream>>>(C, s2_wih, s2_b, A);  // A = XW2
  lstm2_kernel<<<N, 128, 0, stream>>>(A, src, s2_whh, E);  // E = hn2 [N,32]
  sage_out_kernel<32><<<N / 8, 256, 0, stream>>>(C, E, s2_wself, s2_wneigh,
                                                 s2_bias, B);  // B = x2 [N,32]

  // ---- Final MLP ----
  final_kernel<<<N / 256, 256, 0, stream>>>(D, B, f1_w, f1_b, f2_w, f2_b, (float*)d_out);
}

// Round 7
// 529.661 us; speedup vs baseline: 1.1937x; 1.0232x over previous
//
#include <hip/hip_runtime.h>
#include <hip/hip_bf16.h>

#define NNODES 32768
#define DEG 16

__device__ __forceinline__ float sigmoidf_(float x) { return 1.f / (1.f + __expf(-x)); }
__device__ __forceinline__ float tanhf_(float x) { return 1.f - 2.f / (__expf(2.f * x) + 1.f); }

// ---------------------------------------------------------------------------
// Fused triple FC (same input, three weight sets): out_z = in @ W_z + b_z.
// ---------------------------------------------------------------------------
template <int FI, int FO>
__global__ __launch_bounds__(256) void fc3_kernel(
    const float* __restrict__ in,
    const float* __restrict__ W0, const float* __restrict__ B0, float* __restrict__ O0,
    const float* __restrict__ W1, const float* __restrict__ B1, float* __restrict__ O1,
    const float* __restrict__ W2, const float* __restrict__ B2, float* __restrict__ O2) {
  constexpr int ROWS = 32;
  constexpr int FOT = (FO < 64) ? FO : 64;
  constexpr int NJ = FOT;
  constexpr int RSL = 256 / NJ;
  constexpr int R = ROWS / RSL;
  constexpr int PFI = (FI + 4) & ~3;
  __shared__ float w_s[FI * FOT];
  __shared__ float in_s[ROWS * PFI];
  __shared__ float b_s[FOT];
  const float* W = (blockIdx.z == 0) ? W0 : (blockIdx.z == 1) ? W1 : W2;
  const float* bias = (blockIdx.z == 0) ? B0 : (blockIdx.z == 1) ? B1 : B2;
  float* out = (blockIdx.z == 0) ? O0 : (blockIdx.z == 1) ? O1 : O2;
  const int t = threadIdx.x;
  const int rowBase = blockIdx.x * ROWS;
  const int colBase = blockIdx.y * FOT;
  for (int idx = t; idx < FI * FOT; idx += 256) {
    int k = idx / FOT, jj = idx - k * FOT;
    w_s[idx] = W[(size_t)k * FO + colBase + jj];
  }
  if (t < FOT) b_s[t] = bias[colBase + t];
  for (int idx = t; idx < ROWS * FI; idx += 256) {
    int r = idx / FI, k = idx - r * FI;
    in_s[r * PFI + k] = in[(size_t)(rowBase + r) * FI + k];
  }
  __syncthreads();
  const int jj = t % NJ;
  const int rslot = t / NJ;
  float acc[R];
#pragma unroll
  for (int r = 0; r < R; r++) acc[r] = b_s[jj];
  constexpr int K4 = FI / 4;
#pragma unroll
  for (int k4 = 0; k4 < K4; k4++) {
    float wv0 = w_s[(4 * k4 + 0) * FOT + jj];
    float wv1 = w_s[(4 * k4 + 1) * FOT + jj];
    float wv2 = w_s[(4 * k4 + 2) * FOT + jj];
    float wv3 = w_s[(4 * k4 + 3) * FOT + jj];
#pragma unroll
    for (int r = 0; r < R; r++) {
      float4 ip = *(const float4*)&in_s[(rslot * R + r) * PFI + 4 * k4];
      acc[r] += ip.x * wv0 + ip.y * wv1 + ip.z * wv2 + ip.w * wv3;
    }
  }
#pragma unroll
  for (int k = 4 * K4; k < FI; k++) {
    float wv = w_s[k * FOT + jj];
#pragma unroll
    for (int r = 0; r < R; r++) acc[r] += in_s[(rslot * R + r) * PFI + k] * wv;
  }
#pragma unroll
  for (int r = 0; r < R; r++)
    out[(size_t)(rowBase + rslot * R + r) * FO + colBase + jj] = acc[r];
}

// ---------------------------------------------------------------------------
// Single FC for XW2 = x1 @ wih.T + b  (W given [FO][FI], used transposed)
// ---------------------------------------------------------------------------
template <int FI, int FO>
__global__ __launch_bounds__(256) void fct_kernel(const float* __restrict__ in,
                                                  const float* __restrict__ W,
                                                  const float* __restrict__ bias,
                                                  float* __restrict__ out) {
  constexpr int ROWS = 32;
  constexpr int FOT = (FO < 64) ? FO : 64;
  constexpr int NJ = FOT;
  constexpr int RSL = 256 / NJ;
  constexpr int R = ROWS / RSL;
  constexpr int PFI = (FI + 4) & ~3;
  __shared__ float w_s[FI * FOT];
  __shared__ float in_s[ROWS * PFI];
  __shared__ float b_s[FOT];
  const int t = threadIdx.x;
  const int rowBase = blockIdx.x * ROWS;
  const int colBase = blockIdx.y * FOT;
  for (int idx = t; idx < FI * FOT; idx += 256) {
    int k = idx / FOT, jj = idx - k * FOT;
    w_s[idx] = W[(size_t)(colBase + jj) * FI + k];
  }
  if (t < FOT) b_s[t] = bias[colBase + t];
  for (int idx = t; idx < ROWS * FI; idx += 256) {
    int r = idx / FI, k = idx - r * FI;
    in_s[r * PFI + k] = in[(size_t)(rowBase + r) * FI + k];
  }
  __syncthreads();
  const int jj = t % NJ;
  const int rslot = t / NJ;
  float acc[R];
#pragma unroll
  for (int r = 0; r < R; r++) acc[r] = b_s[jj];
  constexpr int K4 = FI / 4;
#pragma unroll
  for (int k4 = 0; k4 < K4; k4++) {
    float wv0 = w_s[(4 * k4 + 0) * FOT + jj];
    float wv1 = w_s[(4 * k4 + 1) * FOT + jj];
    float wv2 = w_s[(4 * k4 + 2) * FOT + jj];
    float wv3 = w_s[(4 * k4 + 3) * FOT + jj];
#pragma unroll
    for (int r = 0; r < R; r++) {
      float4 ip = *(const float4*)&in_s[(rslot * R + r) * PFI + 4 * k4];
      acc[r] += ip.x * wv0 + ip.y * wv1 + ip.z * wv2 + ip.w * wv3;
    }
  }
#pragma unroll
  for (int r = 0; r < R; r++)
    out[(size_t)(rowBase + rslot * R + r) * FO + colBase + jj] = acc[r];
}

// ---------------------------------------------------------------------------
// GATv2 attention + epilogue (unchanged).
// ---------------------------------------------------------------------------
template <int H, bool ELU>
__global__ __launch_bounds__(256) void gat_kernel(const float* __restrict__ fs,
                                                  const float* __restrict__ fd,
                                                  const float* __restrict__ lin,
                                                  const int* __restrict__ src,
                                                  const float* __restrict__ attn,
                                                  const float* __restrict__ bias,
                                                  float* __restrict__ out) {
  constexpr int F = H * 32;
  const int lane = threadIdx.x & 63;
  const int wave = threadIdx.x >> 6;
  const int G = lane >> 4, li = lane & 15;
  int node, f0;
  if (H == 4) {
    node = blockIdx.x * 4 + wave;
    f0 = 2 * lane;
  } else {
    node = blockIdx.x * 16 + wave * 4 + G;
    f0 = 2 * li;
  }
  const int srcv = src[(size_t)node * DEG + li];
  const float2 fdv = *(const float2*)&fd[(size_t)node * F + f0];
  const float a0 = attn[f0];
  const float a1 = attn[f0 + 1];
  float m = -1e30f, s = 0.f, acc0 = 0.f, acc1 = 0.f;
  int sd = __shfl(srcv, (lane & 48), 64);
  float2 fsv = *(const float2*)&fs[(size_t)sd * F + f0];
#pragma unroll
  for (int d = 0; d < DEG; d++) {
    float2 cur = fsv;
    if (d < DEG - 1) {
      int sn = __shfl(srcv, (lane & 48) | (d + 1), 64);
      fsv = *(const float2*)&fs[(size_t)sn * F + f0];
    }
    float e0 = cur.x + fdv.x; e0 = (e0 > 0.f) ? e0 : 0.2f * e0;
    float e1 = cur.y + fdv.y; e1 = (e1 > 0.f) ? e1 : 0.2f * e1;
    float p = e0 * a0 + e1 * a1;
    p += __shfl_xor(p, 1, 64);
    p += __shfl_xor(p, 2, 64);
    p += __shfl_xor(p, 4, 64);
    p += __shfl_xor(p, 8, 64);
    float nm = fmaxf(m, p);
    float ex = __expf(p - nm);
    float sc = __expf(m - nm);
    s = s * sc + ex;
    acc0 = acc0 * sc + ex * cur.x;
    acc1 = acc1 * sc + ex * cur.y;
    m = nm;
  }
  float inv = 1.f / s;
  float2 lv = *(const float2*)&lin[(size_t)node * F + f0];
  float o0 = acc0 * inv + lv.x + bias[f0];
  float o1 = acc1 * inv + lv.y + bias[f0 + 1];
  if (ELU) {
    o0 = (o0 > 0.f) ? o0 : __expf(o0) - 1.f;
    o1 = (o1 > 0.f) ? o1 : __expf(o1) - 1.f;
  }
  *(float2*)&out[(size_t)node * F + f0] = make_float2(o0, o1);
}

// ---------------------------------------------------------------------------
// SAGE-1 input projection: FW[n][20] = feat[n][5] @ wih.T + b   (thread/node)
// ---------------------------------------------------------------------------
__global__ __launch_bounds__(256) void fw1_kernel(const float* __restrict__ feat,
                                                  const float* __restrict__ wih,
                                                  const float* __restrict__ b,
                                                  float* __restrict__ out) {
  __shared__ float w_s[100];
  __shared__ float b_s[20];
  if (threadIdx.x < 100) w_s[threadIdx.x] = wih[threadIdx.x];
  if (threadIdx.x < 20) b_s[threadIdx.x] = b[threadIdx.x];
  __syncthreads();
  const int n = blockIdx.x * 256 + threadIdx.x;
  float f[5];
#pragma unroll
  for (int k = 0; k < 5; k++) f[k] = feat[(size_t)n * 5 + k];
#pragma unroll
  for (int j = 0; j < 20; j++) {
    float a = b_s[j];
#pragma unroll
    for (int k = 0; k < 5; k++) a += f[k] * w_s[j * 5 + k];
    out[(size_t)n * 20 + j] = a;
  }
}

// ---------------------------------------------------------------------------
// SAGE-1: LSTM (hidden=5, thread/node) + fused output projection (unchanged).
// ---------------------------------------------------------------------------
__global__ __attribute__((amdgpu_waves_per_eu(1, 4))) __launch_bounds__(256)
void lstm1s_kernel(const float* __restrict__ FW, const int* __restrict__ src,
                   const float* __restrict__ whh, const float* __restrict__ feat,
                   const float* __restrict__ wself, const float* __restrict__ wneigh,
                   const float* __restrict__ bias, float* __restrict__ x1out) {
  __shared__ float w_s[100];   // whh [20][5]
  __shared__ float ws_s[160];  // wself [5][32]
  __shared__ float wn_s[160];  // wneigh [5][32]
  __shared__ float b_s[32];
  if (threadIdx.x < 100) w_s[threadIdx.x] = whh[threadIdx.x];
  if (threadIdx.x < 160) {
    ws_s[threadIdx.x] = wself[threadIdx.x];
    wn_s[threadIdx.x] = wneigh[threadIdx.x];
  }
  if (threadIdx.x < 32) b_s[threadIdx.x] = bias[threadIdx.x];
  __syncthreads();
  const int n = blockIdx.x * 256 + threadIdx.x;
  const int* sp = src + (size_t)n * DEG;
  float f[5];
#pragma unroll
  for (int k = 0; k < 5; k++) f[k] = feat[(size_t)n * 5 + k];
  float h[5] = {0, 0, 0, 0, 0}, c[5] = {0, 0, 0, 0, 0};
  int sd = sp[0];
  float4 p0 = *(const float4*)&FW[(size_t)sd * 20 + 0];
  float4 p1 = *(const float4*)&FW[(size_t)sd * 20 + 4];
  float4 p2 = *(const float4*)&FW[(size_t)sd * 20 + 8];
  float4 p3 = *(const float4*)&FW[(size_t)sd * 20 + 12];
  float4 p4 = *(const float4*)&FW[(size_t)sd * 20 + 16];
  for (int d = 0; d < DEG; d++) {
    float g[20];
    g[0] = p0.x; g[1] = p0.y; g[2] = p0.z; g[3] = p0.w;
    g[4] = p1.x; g[5] = p1.y; g[6] = p1.z; g[7] = p1.w;
    g[8] = p2.x; g[9] = p2.y; g[10] = p2.z; g[11] = p2.w;
    g[12] = p3.x; g[13] = p3.y; g[14] = p3.z; g[15] = p3.w;
    g[16] = p4.x; g[17] = p4.y; g[18] = p4.z; g[19] = p4.w;
    if (d < DEG - 1) {
      int sn = sp[d + 1];
      p0 = *(const float4*)&FW[(size_t)sn * 20 + 0];
      p1 = *(const float4*)&FW[(size_t)sn * 20 + 4];
      p2 = *(const float4*)&FW[(size_t)sn * 20 + 8];
      p3 = *(const float4*)&FW[(size_t)sn * 20 + 12];
      p4 = *(const float4*)&FW[(size_t)sn * 20 + 16];
    }
#pragma unroll
    for (int j = 0; j < 20; j++) {
#pragma unroll
      for (int k = 0; k < 5; k++) g[j] += h[k] * w_s[j * 5 + k];
    }
#pragma unroll
    for (int k = 0; k < 5; k++) {
      float iv = sigmoidf_(g[k]);
      float fv = sigmoidf_(g[5 + k]);
      float gv = tanhf_(g[10 + k]);
      float ov = sigmoidf_(g[15 + k]);
      c[k] = fv * c[k] + iv * gv;
      h[k] = ov * tanhf_(c[k]);
    }
  }
#pragma unroll
  for (int j = 0; j < 32; j++) {
    float a = b_s[j];
#pragma unroll
    for (int k = 0; k < 5; k++) a += f[k] * ws_s[k * 32 + j] + h[k] * wn_s[k * 32 + j];
    x1out[(size_t)n * 32 + j] = fmaxf(a, 0.f);
  }
}

// ---------------------------------------------------------------------------
// SAGE-2 LSTM v4: block = 128 = 2 waves = 1 node; xw staged in LDS.
// R6 post-mortem: asm fences pin VALUES but not REGISTERS — the RA spilled
// w[]+xw[] to scratch anyway (VGPR_Count=40 < 48 fenced floats) and scratch
// allocation capped occupancy at 62%. Fix: shrink per-lane live state below
// the 64-reg budget for real. The 16 gathered xw floats go to LDS
// (xw_lds[16][128]; staged once, all 16 gathers in flight); per step each
// lane does one 2-way-conflict-free ds_read_b32. Only w[32] stays in regs.
// ---------------------------------------------------------------------------
__global__ __launch_bounds__(128)
void lstm2_kernel(const float* __restrict__ XW, const int* __restrict__ src,
                  const float* __restrict__ whh, float* __restrict__ hn_out) {
  __shared__ float xw_lds[DEG * 128];
  __shared__ float h_lds[32];
  __shared__ float act_lds[128];
  const int t = threadIdx.x;       // 0..127
  const int lane = t & 63;
  const int half = t >> 6;         // wave within block
  const int node = blockIdx.x;
  const int j = half * 64 + lane;  // owned gate row 0..127
  // stage xw: all DEG gathers issued back-to-back (one exposed round-trip)
  const int* sp = src + (size_t)node * DEG;
  {
    float tmp[DEG];
#pragma unroll
    for (int q = 0; q < DEG / 4; q++) {
      int4 iq = *(const int4*)&sp[4 * q];
      tmp[4 * q + 0] = XW[(size_t)iq.x * 128 + j];
      tmp[4 * q + 1] = XW[(size_t)iq.y * 128 + j];
      tmp[4 * q + 2] = XW[(size_t)iq.z * 128 + j];
      tmp[4 * q + 3] = XW[(size_t)iq.w * 128 + j];
    }
#pragma unroll
    for (int d = 0; d < DEG; d++) xw_lds[d * 128 + j] = tmp[d];
  }
  // whh rows into regs (fits the default 64-reg budget: 32 w + ~16 misc)
  float w[32];
#pragma unroll
  for (int k4 = 0; k4 < 8; k4++) {
    float4 a = *(const float4*)&whh[(size_t)j * 32 + 4 * k4];
    w[4 * k4 + 0] = a.x; w[4 * k4 + 1] = a.y;
    w[4 * k4 + 2] = a.z; w[4 * k4 + 3] = a.w;
  }
  if (t < 32) h_lds[t] = 0.f;
  __syncthreads();
  float c = 0.f, h = 0.f;
#pragma unroll
  for (int d = 0; d < DEG; d++) {
    float g = xw_lds[d * 128 + j];
#pragma unroll
    for (int k4 = 0; k4 < 8; k4++) {
      float4 h4 = *(const float4*)&h_lds[4 * k4];  // same-address broadcast
      g += h4.x * w[4 * k4 + 0] + h4.y * w[4 * k4 + 1] +
           h4.z * w[4 * k4 + 2] + h4.w * w[4 * k4 + 3];
    }
    float act;
    if (half == 0) act = sigmoidf_(g);                   // i | f rows
    else act = (lane < 32) ? tanhf_(g) : sigmoidf_(g);   // g | o rows
    act_lds[j] = act;
    __syncthreads();
    if (t < 32) {
      float iv = act_lds[t];
      float fv = act_lds[32 + t];
      float gv = act_lds[64 + t];
      float ov = act_lds[96 + t];
      c = fv * c + iv * gv;
      h = ov * tanhf_(c);
      h_lds[t] = h;
    }
    __syncthreads();
  }
  if (t < 32) hn_out[(size_t)node * 32 + t] = h;
}

// ---------------------------------------------------------------------------
// SAGE output: out = relu(in @ wself + hn @ wneigh + bias), FO=32
// ---------------------------------------------------------------------------
template <int FI>
__global__ __launch_bounds__(256) void sage_out_kernel(const float* __restrict__ in,
                                                       const float* __restrict__ hn,
                                                       const float* __restrict__ wself,
                                                       const float* __restrict__ wneigh,
                                                       const float* __restrict__ bias,
                                                       float* __restrict__ out) {
  __shared__ float ws_s[FI * 32];
  __shared__ float wn_s[FI * 32];
  __shared__ float b_s[32];
  for (int idx = threadIdx.x; idx < FI * 32; idx += 256) {
    ws_s[idx] = wself[idx];
    wn_s[idx] = wneigh[idx];
  }
  if (threadIdx.x < 32) b_s[threadIdx.x] = bias[threadIdx.x];
  __syncthreads();
  const int n = blockIdx.x * 8 + (threadIdx.x >> 5);
  const int j = threadIdx.x & 31;
  float a = b_s[j];
#pragma unroll
  for (int k = 0; k < FI; k++) a += in[(size_t)n * FI + k] * ws_s[k * 32 + j];
#pragma unroll
  for (int k = 0; k < FI; k++) a += hn[(size_t)n * FI + k] * wn_s[k * 32 + j];
  out[(size_t)n * 32 + j] = fmaxf(a, 0.f);
}

// ---------------------------------------------------------------------------
// Final MLP: out = relu([gat,x2] @ f1 + b1) @ f2 + b2   (thread per node)
// ---------------------------------------------------------------------------
__global__ __attribute__((amdgpu_waves_per_eu(4, 4))) __launch_bounds__(256)
void final_kernel(const float* __restrict__ gat,
                  const float* __restrict__ x2,
                  const float* __restrict__ f1w,
                  const float* __restrict__ f1b,
                  const float* __restrict__ f2w,
                  const float* __restrict__ f2b,
                  float* __restrict__ out) {
  __shared__ float w1_s[64 * 16];
  __shared__ float b1_s[16];
  __shared__ float w2_s[16];
  for (int idx = threadIdx.x; idx < 1024; idx += 256) w1_s[idx] = f1w[idx];
  if (threadIdx.x < 16) {
    b1_s[threadIdx.x] = f1b[threadIdx.x];
    w2_s[threadIdx.x] = f2w[threadIdx.x];
  }
  __syncthreads();
  const int n = blockIdx.x * 256 + threadIdx.x;
  float z[64];
#pragma unroll
  for (int k = 0; k < 32; k += 4) {
    float4 a = *(const float4*)&gat[(size_t)n * 32 + k];
    z[k] = a.x; z[k + 1] = a.y; z[k + 2] = a.z; z[k + 3] = a.w;
    float4 b = *(const float4*)&x2[(size_t)n * 32 + k];
    z[32 + k] = b.x; z[32 + k + 1] = b.y; z[32 + k + 2] = b.z; z[32 + k + 3] = b.w;
  }
  float o = f2b[0];
#pragma unroll
  for (int j = 0; j < 16; j++) {
    float a = b1_s[j];
#pragma unroll
    for (int k = 0; k < 64; k++) a += z[k] * w1_s[k * 16 + j];
    o += fmaxf(a, 0.f) * w2_s[j];
  }
  out[n] = o;
}

extern "C" void kernel_launch(void* const* d_in, const int* in_sizes, int n_in,
                              void* d_out, int out_size, void* d_ws, size_t ws_size,
                              hipStream_t stream) {
  const int N = NNODES;
  const float* feat = (const float*)d_in[0];
  const int* src = (const int*)d_in[1];
  const float* g0_ws = (const float*)d_in[2];
  const float* g0_bs = (const float*)d_in[3];
  const float* g0_wd = (const float*)d_in[4];
  const float* g0_bd = (const float*)d_in[5];
  const float* g0_attn = (const float*)d_in[6];
  const float* g0_bias = (const float*)d_in[7];
  const float* l0_w = (const float*)d_in[8];
  const float* l0_b = (const float*)d_in[9];
  const float* g1_ws = (const float*)d_in[10];
  const float* g1_bs = (const float*)d_in[11];
  const float* g1_wd = (const float*)d_in[12];
  const float* g1_bd = (const float*)d_in[13];
  const float* g1_attn = (const float*)d_in[14];
  const float* g1_bias = (const float*)d_in[15];
  const float* l1_w = (const float*)d_in[16];
  const float* l1_b = (const float*)d_in[17];
  const float* g2_ws = (const float*)d_in[18];
  const float* g2_bs = (const float*)d_in[19];
  const float* g2_wd = (const float*)d_in[20];
  const float* g2_bd = (const float*)d_in[21];
  const float* g2_attn = (const float*)d_in[22];
  const float* g2_bias = (const float*)d_in[23];
  const float* l2_w = (const float*)d_in[24];
  const float* l2_b = (const float*)d_in[25];
  const float* s1_wih = (const float*)d_in[26];
  const float* s1_whh = (const float*)d_in[27];
  const float* s1_b = (const float*)d_in[28];
  const float* s1_wself = (const float*)d_in[29];
  const float* s1_wneigh = (const float*)d_in[30];
  const float* s1_bias = (const float*)d_in[31];
  const float* s2_wih = (const float*)d_in[32];
  const float* s2_whh = (const float*)d_in[33];
  const float* s2_b = (const float*)d_in[34];
  const float* s2_wself = (const float*)d_in[35];
  const float* s2_wneigh = (const float*)d_in[36];
  const float* s2_bias = (const float*)d_in[37];
  const float* f1_w = (const float*)d_in[38];
  const float* f1_b = (const float*)d_in[39];
  const float* f2_w = (const float*)d_in[40];
  const float* f2_b = (const float*)d_in[41];

  float* A = (float*)d_ws;                // N*128
  float* B = A + (size_t)N * 128;
  float* C = B + (size_t)N * 128;
  float* D = C + (size_t)N * 128;
  float* E = D + (size_t)N * 128;         // total 84 MB

  // ---- GAT layer 0 (fi=5, H=4): fs->A fd->B lin->C ----
  fc3_kernel<5, 128><<<dim3(N / 32, 2, 3), 256, 0, stream>>>(
      feat, g0_ws, g0_bs, A, g0_wd, g0_bd, B, l0_w, l0_b, C);
  gat_kernel<4, true><<<N / 4, 256, 0, stream>>>(A, B, C, src, g0_attn, g0_bias, D);  // D = h1

  // ---- GAT layer 1 (fi=128, H=4) ----
  fc3_kernel<128, 128><<<dim3(N / 32, 2, 3), 256, 0, stream>>>(
      D, g1_ws, g1_bs, A, g1_wd, g1_bd, B, l1_w, l1_b, C);
  gat_kernel<4, true><<<N / 4, 256, 0, stream>>>(A, B, C, src, g1_attn, g1_bias, E);  // E = h2

  // ---- GAT layer 2 (fi=128, H=1) ----
  fc3_kernel<128, 32><<<dim3(N / 32, 1, 3), 256, 0, stream>>>(
      E, g2_ws, g2_bs, A, g2_wd, g2_bd, B, l2_w, l2_b, C);
  gat_kernel<1, false><<<N / 16, 256, 0, stream>>>(A, B, C, src, g2_attn, g2_bias, D);  // D = gat [N,32]

  // ---- SAGE layer 1 ----
  fw1_kernel<<<N / 256, 256, 0, stream>>>(feat, s1_wih, s1_b, E);  // E = FW1 [N,20]
  lstm1s_kernel<<<N / 256, 256, 0, stream>>>(E, src, s1_whh, feat, s1_wself,
                                             s1_wneigh, s1_bias, C);  // C = x1 [N,32]

  // ---- SAGE layer 2 ----
  fct_kernel<32, 128><<<dim3(N / 32, 2), 256, 0, stream>>>(C, s2_wih, s2_b, A);  // A = XW2
  lstm2_kernel<<<N, 128, 0, stream>>>(A, src, s2_whh, E);  // E = hn2 [N,32]
  sage_out_kernel<32><<<N / 8, 256, 0, stream>>>(C, E, s2_wself, s2_wneigh,
                                                 s2_bias, B);  // B = x2 [N,32]

  // ---- Final MLP ----
  final_kernel<<<N / 256, 256, 0, stream>>>(D, B, f1_w, f1_b, f2_w, f2_b, (float*)d_out);
}

// Round 8
// 480.433 us; speedup vs baseline: 1.3160x; 1.1025x over previous
//
#include <hip/hip_runtime.h>
#include <hip/hip_bf16.h>

#define NNODES 32768
#define DEG 16

__device__ __forceinline__ float sigmoidf_(float x) { return 1.f / (1.f + __expf(-x)); }
__device__ __forceinline__ float tanhf_(float x) { return 1.f - 2.f / (__expf(2.f * x) + 1.f); }

typedef __attribute__((ext_vector_type(8))) short bf16x8;
typedef __attribute__((ext_vector_type(4))) float f32x4;

__device__ __forceinline__ unsigned short f2bf_(float x) {
  __hip_bfloat16 b = __float2bfloat16(x);
  union { __hip_bfloat16 b; unsigned short u; } cv;
  cv.b = b;
  return cv.u;
}
__device__ __forceinline__ float bf2f_(unsigned short u) {
  union { unsigned short u; __hip_bfloat16 b; } cv;
  cv.u = u;
  return __bfloat162float(cv.b);
}
// split 8 fp32 into hi/lo bf16 fragments (error ~2^-16 relative)
__device__ __forceinline__ void pack_hilo_(const float* v, bf16x8& hi, bf16x8& lo) {
#pragma unroll
  for (int j = 0; j < 8; j++) {
    unsigned short h = f2bf_(v[j]);
    float resid = v[j] - bf2f_(h);
    hi[j] = (short)h;
    lo[j] = (short)f2bf_(resid);
  }
}

// ---------------------------------------------------------------------------
// Fused triple FC (same input, three weight sets): out_z = in @ W_z + b_z.
// ---------------------------------------------------------------------------
template <int FI, int FO>
__global__ __launch_bounds__(256) void fc3_kernel(
    const float* __restrict__ in,
    const float* __restrict__ W0, const float* __restrict__ B0, float* __restrict__ O0,
    const float* __restrict__ W1, const float* __restrict__ B1, float* __restrict__ O1,
    const float* __restrict__ W2, const float* __restrict__ B2, float* __restrict__ O2) {
  constexpr int ROWS = 32;
  constexpr int FOT = (FO < 64) ? FO : 64;
  constexpr int NJ = FOT;
  constexpr int RSL = 256 / NJ;
  constexpr int R = ROWS / RSL;
  constexpr int PFI = (FI + 4) & ~3;
  __shared__ float w_s[FI * FOT];
  __shared__ float in_s[ROWS * PFI];
  __shared__ float b_s[FOT];
  const float* W = (blockIdx.z == 0) ? W0 : (blockIdx.z == 1) ? W1 : W2;
  const float* bias = (blockIdx.z == 0) ? B0 : (blockIdx.z == 1) ? B1 : B2;
  float* out = (blockIdx.z == 0) ? O0 : (blockIdx.z == 1) ? O1 : O2;
  const int t = threadIdx.x;
  const int rowBase = blockIdx.x * ROWS;
  const int colBase = blockIdx.y * FOT;
  for (int idx = t; idx < FI * FOT; idx += 256) {
    int k = idx / FOT, jj = idx - k * FOT;
    w_s[idx] = W[(size_t)k * FO + colBase + jj];
  }
  if (t < FOT) b_s[t] = bias[colBase + t];
  for (int idx = t; idx < ROWS * FI; idx += 256) {
    int r = idx / FI, k = idx - r * FI;
    in_s[r * PFI + k] = in[(size_t)(rowBase + r) * FI + k];
  }
  __syncthreads();
  const int jj = t % NJ;
  const int rslot = t / NJ;
  float acc[R];
#pragma unroll
  for (int r = 0; r < R; r++) acc[r] = b_s[jj];
  constexpr int K4 = FI / 4;
#pragma unroll
  for (int k4 = 0; k4 < K4; k4++) {
    float wv0 = w_s[(4 * k4 + 0) * FOT + jj];
    float wv1 = w_s[(4 * k4 + 1) * FOT + jj];
    float wv2 = w_s[(4 * k4 + 2) * FOT + jj];
    float wv3 = w_s[(4 * k4 + 3) * FOT + jj];
#pragma unroll
    for (int r = 0; r < R; r++) {
      float4 ip = *(const float4*)&in_s[(rslot * R + r) * PFI + 4 * k4];
      acc[r] += ip.x * wv0 + ip.y * wv1 + ip.z * wv2 + ip.w * wv3;
    }
  }
#pragma unroll
  for (int k = 4 * K4; k < FI; k++) {
    float wv = w_s[k * FOT + jj];
#pragma unroll
    for (int r = 0; r < R; r++) acc[r] += in_s[(rslot * R + r) * PFI + k] * wv;
  }
#pragma unroll
  for (int r = 0; r < R; r++)
    out[(size_t)(rowBase + rslot * R + r) * FO + colBase + jj] = acc[r];
}

// ---------------------------------------------------------------------------
// Single FC for XW2 = x1 @ wih.T + b  (W given [FO][FI], used transposed)
// ---------------------------------------------------------------------------
template <int FI, int FO>
__global__ __launch_bounds__(256) void fct_kernel(const float* __restrict__ in,
                                                  const float* __restrict__ W,
                                                  const float* __restrict__ bias,
                                                  float* __restrict__ out) {
  constexpr int ROWS = 32;
  constexpr int FOT = (FO < 64) ? FO : 64;
  constexpr int NJ = FOT;
  constexpr int RSL = 256 / NJ;
  constexpr int R = ROWS / RSL;
  constexpr int PFI = (FI + 4) & ~3;
  __shared__ float w_s[FI * FOT];
  __shared__ float in_s[ROWS * PFI];
  __shared__ float b_s[FOT];
  const int t = threadIdx.x;
  const int rowBase = blockIdx.x * ROWS;
  const int colBase = blockIdx.y * FOT;
  for (int idx = t; idx < FI * FOT; idx += 256) {
    int k = idx / FOT, jj = idx - k * FOT;
    w_s[idx] = W[(size_t)(colBase + jj) * FI + k];
  }
  if (t < FOT) b_s[t] = bias[colBase + t];
  for (int idx = t; idx < ROWS * FI; idx += 256) {
    int r = idx / FI, k = idx - r * FI;
    in_s[r * PFI + k] = in[(size_t)(rowBase + r) * FI + k];
  }
  __syncthreads();
  const int jj = t % NJ;
  const int rslot = t / NJ;
  float acc[R];
#pragma unroll
  for (int r = 0; r < R; r++) acc[r] = b_s[jj];
  constexpr int K4 = FI / 4;
#pragma unroll
  for (int k4 = 0; k4 < K4; k4++) {
    float wv0 = w_s[(4 * k4 + 0) * FOT + jj];
    float wv1 = w_s[(4 * k4 + 1) * FOT + jj];
    float wv2 = w_s[(4 * k4 + 2) * FOT + jj];
    float wv3 = w_s[(4 * k4 + 3) * FOT + jj];
#pragma unroll
    for (int r = 0; r < R; r++) {
      float4 ip = *(const float4*)&in_s[(rslot * R + r) * PFI + 4 * k4];
      acc[r] += ip.x * wv0 + ip.y * wv1 + ip.z * wv2 + ip.w * wv3;
    }
  }
#pragma unroll
  for (int r = 0; r < R; r++)
    out[(size_t)(rowBase + rslot * R + r) * FO + colBase + jj] = acc[r];
}

// ---------------------------------------------------------------------------
// GATv2 attention + epilogue (unchanged).
// ---------------------------------------------------------------------------
template <int H, bool ELU>
__global__ __launch_bounds__(256) void gat_kernel(const float* __restrict__ fs,
                                                  const float* __restrict__ fd,
                                                  const float* __restrict__ lin,
                                                  const int* __restrict__ src,
                                                  const float* __restrict__ attn,
                                                  const float* __restrict__ bias,
                                                  float* __restrict__ out) {
  constexpr int F = H * 32;
  const int lane = threadIdx.x & 63;
  const int wave = threadIdx.x >> 6;
  const int G = lane >> 4, li = lane & 15;
  int node, f0;
  if (H == 4) {
    node = blockIdx.x * 4 + wave;
    f0 = 2 * lane;
  } else {
    node = blockIdx.x * 16 + wave * 4 + G;
    f0 = 2 * li;
  }
  const int srcv = src[(size_t)node * DEG + li];
  const float2 fdv = *(const float2*)&fd[(size_t)node * F + f0];
  const float a0 = attn[f0];
  const float a1 = attn[f0 + 1];
  float m = -1e30f, s = 0.f, acc0 = 0.f, acc1 = 0.f;
  int sd = __shfl(srcv, (lane & 48), 64);
  float2 fsv = *(const float2*)&fs[(size_t)sd * F + f0];
#pragma unroll
  for (int d = 0; d < DEG; d++) {
    float2 cur = fsv;
    if (d < DEG - 1) {
      int sn = __shfl(srcv, (lane & 48) | (d + 1), 64);
      fsv = *(const float2*)&fs[(size_t)sn * F + f0];
    }
    float e0 = cur.x + fdv.x; e0 = (e0 > 0.f) ? e0 : 0.2f * e0;
    float e1 = cur.y + fdv.y; e1 = (e1 > 0.f) ? e1 : 0.2f * e1;
    float p = e0 * a0 + e1 * a1;
    p += __shfl_xor(p, 1, 64);
    p += __shfl_xor(p, 2, 64);
    p += __shfl_xor(p, 4, 64);
    p += __shfl_xor(p, 8, 64);
    float nm = fmaxf(m, p);
    float ex = __expf(p - nm);
    float sc = __expf(m - nm);
    s = s * sc + ex;
    acc0 = acc0 * sc + ex * cur.x;
    acc1 = acc1 * sc + ex * cur.y;
    m = nm;
  }
  float inv = 1.f / s;
  float2 lv = *(const float2*)&lin[(size_t)node * F + f0];
  float o0 = acc0 * inv + lv.x + bias[f0];
  float o1 = acc1 * inv + lv.y + bias[f0 + 1];
  if (ELU) {
    o0 = (o0 > 0.f) ? o0 : __expf(o0) - 1.f;
    o1 = (o1 > 0.f) ? o1 : __expf(o1) - 1.f;
  }
  *(float2*)&out[(size_t)node * F + f0] = make_float2(o0, o1);
}

// ---------------------------------------------------------------------------
// SAGE-1 input projection: FW[n][20] = feat[n][5] @ wih.T + b   (thread/node)
// ---------------------------------------------------------------------------
__global__ __launch_bounds__(256) void fw1_kernel(const float* __restrict__ feat,
                                                  const float* __restrict__ wih,
                                                  const float* __restrict__ b,
                                                  float* __restrict__ out) {
  __shared__ float w_s[100];
  __shared__ float b_s[20];
  if (threadIdx.x < 100) w_s[threadIdx.x] = wih[threadIdx.x];
  if (threadIdx.x < 20) b_s[threadIdx.x] = b[threadIdx.x];
  __syncthreads();
  const int n = blockIdx.x * 256 + threadIdx.x;
  float f[5];
#pragma unroll
  for (int k = 0; k < 5; k++) f[k] = feat[(size_t)n * 5 + k];
#pragma unroll
  for (int j = 0; j < 20; j++) {
    float a = b_s[j];
#pragma unroll
    for (int k = 0; k < 5; k++) a += f[k] * w_s[j * 5 + k];
    out[(size_t)n * 20 + j] = a;
  }
}

// ---------------------------------------------------------------------------
// SAGE-1: LSTM (hidden=5, thread/node) + fused output projection (unchanged).
// ---------------------------------------------------------------------------
__global__ __attribute__((amdgpu_waves_per_eu(1, 4))) __launch_bounds__(256)
void lstm1s_kernel(const float* __restrict__ FW, const int* __restrict__ src,
                   const float* __restrict__ whh, const float* __restrict__ feat,
                   const float* __restrict__ wself, const float* __restrict__ wneigh,
                   const float* __restrict__ bias, float* __restrict__ x1out) {
  __shared__ float w_s[100];   // whh [20][5]
  __shared__ float ws_s[160];  // wself [5][32]
  __shared__ float wn_s[160];  // wneigh [5][32]
  __shared__ float b_s[32];
  if (threadIdx.x < 100) w_s[threadIdx.x] = whh[threadIdx.x];
  if (threadIdx.x < 160) {
    ws_s[threadIdx.x] = wself[threadIdx.x];
    wn_s[threadIdx.x] = wneigh[threadIdx.x];
  }
  if (threadIdx.x < 32) b_s[threadIdx.x] = bias[threadIdx.x];
  __syncthreads();
  const int n = blockIdx.x * 256 + threadIdx.x;
  const int* sp = src + (size_t)n * DEG;
  float f[5];
#pragma unroll
  for (int k = 0; k < 5; k++) f[k] = feat[(size_t)n * 5 + k];
  float h[5] = {0, 0, 0, 0, 0}, c[5] = {0, 0, 0, 0, 0};
  int sd = sp[0];
  float4 p0 = *(const float4*)&FW[(size_t)sd * 20 + 0];
  float4 p1 = *(const float4*)&FW[(size_t)sd * 20 + 4];
  float4 p2 = *(const float4*)&FW[(size_t)sd * 20 + 8];
  float4 p3 = *(const float4*)&FW[(size_t)sd * 20 + 12];
  float4 p4 = *(const float4*)&FW[(size_t)sd * 20 + 16];
  for (int d = 0; d < DEG; d++) {
    float g[20];
    g[0] = p0.x; g[1] = p0.y; g[2] = p0.z; g[3] = p0.w;
    g[4] = p1.x; g[5] = p1.y; g[6] = p1.z; g[7] = p1.w;
    g[8] = p2.x; g[9] = p2.y; g[10] = p2.z; g[11] = p2.w;
    g[12] = p3.x; g[13] = p3.y; g[14] = p3.z; g[15] = p3.w;
    g[16] = p4.x; g[17] = p4.y; g[18] = p4.z; g[19] = p4.w;
    if (d < DEG - 1) {
      int sn = sp[d + 1];
      p0 = *(const float4*)&FW[(size_t)sn * 20 + 0];
      p1 = *(const float4*)&FW[(size_t)sn * 20 + 4];
      p2 = *(const float4*)&FW[(size_t)sn * 20 + 8];
      p3 = *(const float4*)&FW[(size_t)sn * 20 + 12];
      p4 = *(const float4*)&FW[(size_t)sn * 20 + 16];
    }
#pragma unroll
    for (int j = 0; j < 20; j++) {
#pragma unroll
      for (int k = 0; k < 5; k++) g[j] += h[k] * w_s[j * 5 + k];
    }
#pragma unroll
    for (int k = 0; k < 5; k++) {
      float iv = sigmoidf_(g[k]);
      float fv = sigmoidf_(g[5 + k]);
      float gv = tanhf_(g[10 + k]);
      float ov = sigmoidf_(g[15 + k]);
      c[k] = fv * c[k] + iv * gv;
      h[k] = ov * tanhf_(c[k]);
    }
  }
#pragma unroll
  for (int j = 0; j < 32; j++) {
    float a = b_s[j];
#pragma unroll
    for (int k = 0; k < 5; k++) a += f[k] * ws_s[k * 32 + j] + h[k] * wn_s[k * 32 + j];
    x1out[(size_t)n * 32 + j] = fmaxf(a, 0.f);
  }
}

// ---------------------------------------------------------------------------
// SAGE-2 LSTM v5 (MFMA): ONE WAVE per 16 nodes, zero barriers.
// Per step: G[128 gates x 16 nodes] = W(128x32) @ H(32x16) via 8 MFMA tiles
// (16x16x32_bf16), fp32 recovered with hi/lo bf16 splits of W and H
// (3 MFMAs/tile; dropped lo*lo term ~2^-18 rel).
// Verified layouts (learn_hip m89): A[m][k]: m=lane&15, k=(lane>>4)*8+j;
// B[k][n]: n=lane&15, k=(lane>>4)*8+j; C/D: col=lane&15, row=(lane>>4)*4+reg.
// => lane (q=lane>>4, n=lane&15) gets i,f,g,o of the SAME 8 cells
// {16hh+4q+r} for node n -> activations + c/h update fully in-lane; h->B-frag
// via tiny LDS round-trip. xw: lane's needed chunks are = q (mod 4), matching
// a coalesced 8x b128/step prefetch straight into regs (no LDS staging).
// LDS pad caps occupancy at 2 blocks/CU (grid 512 = exactly resident) so the
// RA targets 2 waves/SIMD (256-reg budget) -- R2..R7 lesson: with tiny LDS it
// targets 8 waves/64 regs and spills every weight array (VGPR 60/48/40/28).
// ---------------------------------------------------------------------------
__global__ __launch_bounds__(256) __attribute__((amdgpu_waves_per_eu(1, 2)))
void lstm2_mfma_kernel(const float* __restrict__ XW, const int* __restrict__ src,
                       const float* __restrict__ whh, float* __restrict__ hn_out) {
  __shared__ float h_lds_all[4 * 16 * 36];
  __shared__ int src_lds_all[4 * 256];
  __shared__ float lds_pad[15000];  // occupancy cap: ~73 KB total -> 2 blocks/CU
  if ((const void*)XW == nullptr) lds_pad[0] = 1.f;  // keep pad allocated
  const int tid = threadIdx.x;
  const int wid = tid >> 6;
  const int lane = tid & 63;
  const int q = lane >> 4;   // quad
  const int n = lane & 15;   // node within group / fragment col
  const int n0 = (blockIdx.x * 4 + wid) * 16;
  float* h_lds = &h_lds_all[wid * 16 * 36];
  int* src_lds = &src_lds_all[wid * 256];

  // stage src transposed to [d][n]
  {
    int4 sv = *(const int4*)&src[(size_t)(n0 + (lane >> 2)) * DEG + 4 * (lane & 3)];
    src_lds[(4 * (lane & 3) + 0) * 16 + (lane >> 2)] = sv.x;
    src_lds[(4 * (lane & 3) + 1) * 16 + (lane >> 2)] = sv.y;
    src_lds[(4 * (lane & 3) + 2) * 16 + (lane >> 2)] = sv.z;
    src_lds[(4 * (lane & 3) + 3) * 16 + (lane >> 2)] = sv.w;
  }

  // W fragments: tile gt covers gate rows 16gt..16gt+15; lane supplies
  // A[m=n][k=8q+j] = whh[16gt+n][8q+j], split hi/lo.
  bf16x8 Whi[8], Wlo[8];
#pragma unroll
  for (int gt = 0; gt < 8; gt++) {
    float wv[8];
    *(float4*)&wv[0] = *(const float4*)&whh[(size_t)(16 * gt + n) * 32 + 8 * q];
    *(float4*)&wv[4] = *(const float4*)&whh[(size_t)(16 * gt + n) * 32 + 8 * q + 4];
    pack_hilo_(wv, Whi[gt], Wlo[gt]);
  }

  bf16x8 Bhi, Blo;
#pragma unroll
  for (int j = 0; j < 8; j++) { Bhi[j] = 0; Blo[j] = 0; }
  float cst[8];
#pragma unroll
  for (int i = 0; i < 8; i++) cst[i] = 0.f;

  // prefetch xw for step 0: t[i] = XW[s][16i+4q .. +3]  (chunk c=4i+q of own node)
  float4 tc[8], tn[8];
  {
    int s0 = src_lds[0 * 16 + n];
    const float* gb = XW + (size_t)s0 * 128;
#pragma unroll
    for (int i = 0; i < 8; i++) tc[i] = *(const float4*)&gb[16 * i + 4 * q];
  }

  float hv[8];
#pragma unroll
  for (int d = 0; d < DEG; d++) {
    // MFMA: G = W * H  (H = prev h; zero at d=0)
    f32x4 D[4][2];
#pragma unroll
    for (int p = 0; p < 4; p++) {
#pragma unroll
      for (int hh = 0; hh < 2; hh++) {
        int gt = p * 2 + hh;
        f32x4 acc = {0.f, 0.f, 0.f, 0.f};
        acc = __builtin_amdgcn_mfma_f32_16x16x32_bf16(Whi[gt], Bhi, acc, 0, 0, 0);
        acc = __builtin_amdgcn_mfma_f32_16x16x32_bf16(Wlo[gt], Bhi, acc, 0, 0, 0);
        acc = __builtin_amdgcn_mfma_f32_16x16x32_bf16(Whi[gt], Blo, acc, 0, 0, 0);
        D[p][hh] = acc;
      }
    }
    // issue next step's xw loads early (covered by activation latency below)
    if (d < DEG - 1) {
      int s = src_lds[(d + 1) * 16 + n];
      const float* gb = XW + (size_t)s * 128;
#pragma unroll
      for (int i = 0; i < 8; i++) tn[i] = *(const float4*)&gb[16 * i + 4 * q];
    }
    // gates + activations; lane's cell for (hh,r) is k = 16hh+4q+r of node n;
    // xw chunk for class p, half hh is tc[2p+hh] (c = 8p+4hh+q, = q mod 4).
#pragma unroll
    for (int hh = 0; hh < 2; hh++) {
      float4 xi = tc[0 + hh];
      float4 xf = tc[2 + hh];
      float4 xg = tc[4 + hh];
      float4 xo = tc[6 + hh];
#pragma unroll
      for (int r = 0; r < 4; r++) {
        float xiv = (r == 0) ? xi.x : (r == 1) ? xi.y : (r == 2) ? xi.z : xi.w;
        float xfv = (r == 0) ? xf.x : (r == 1) ? xf.y : (r == 2) ? xf.z : xf.w;
        float xgv = (r == 0) ? xg.x : (r == 1) ? xg.y : (r == 2) ? xg.z : xg.w;
        float xov = (r == 0) ? xo.x : (r == 1) ? xo.y : (r == 2) ? xo.z : xo.w;
        int ci = hh * 4 + r;
        float iv = sigmoidf_(D[0][hh][r] + xiv);
        float fv = sigmoidf_(D[1][hh][r] + xfv);
        float gv = tanhf_(D[2][hh][r] + xgv);
        float ov = sigmoidf_(D[3][hh][r] + xov);
        cst[ci] = fv * cst[ci] + iv * gv;
        hv[ci] = ov * tanhf_(cst[ci]);
      }
    }
    if (d < DEG - 1) {
      // h -> B-frag layout round-trip (own-wave LDS, in-order, no barrier)
      *(float4*)&h_lds[n * 36 + 0 + 4 * q] = make_float4(hv[0], hv[1], hv[2], hv[3]);
      *(float4*)&h_lds[n * 36 + 16 + 4 * q] = make_float4(hv[4], hv[5], hv[6], hv[7]);
      float hb[8];
      *(float4*)&hb[0] = *(const float4*)&h_lds[n * 36 + 8 * q];
      *(float4*)&hb[4] = *(const float4*)&h_lds[n * 36 + 8 * q + 4];
      pack_hilo_(hb, Bhi, Blo);
#pragma unroll
      for (int i = 0; i < 8; i++) tc[i] = tn[i];
    }
  }
  // final h: cells k = 16hh+4q+r of node n0+n
  *(float4*)&hn_out[(size_t)(n0 + n) * 32 + 0 + 4 * q] = make_float4(hv[0], hv[1], hv[2], hv[3]);
  *(float4*)&hn_out[(size_t)(n0 + n) * 32 + 16 + 4 * q] = make_float4(hv[4], hv[5], hv[6], hv[7]);
}

// ---------------------------------------------------------------------------
// SAGE output: out = relu(in @ wself + hn @ wneigh + bias), FO=32
// ---------------------------------------------------------------------------
template <int FI>
__global__ __launch_bounds__(256) void sage_out_kernel(const float* __restrict__ in,
                                                       const float* __restrict__ hn,
                                                       const float* __restrict__ wself,
                                                       const float* __restrict__ wneigh,
                                                       const float* __restrict__ bias,
                                                       float* __restrict__ out) {
  __shared__ float ws_s[FI * 32];
  __shared__ float wn_s[FI * 32];
  __shared__ float b_s[32];
  for (int idx = threadIdx.x; idx < FI * 32; idx += 256) {
    ws_s[idx] = wself[idx];
    wn_s[idx] = wneigh[idx];
  }
  if (threadIdx.x < 32) b_s[threadIdx.x] = bias[threadIdx.x];
  __syncthreads();
  const int n = blockIdx.x * 8 + (threadIdx.x >> 5);
  const int j = threadIdx.x & 31;
  float a = b_s[j];
#pragma unroll
  for (int k = 0; k < FI; k++) a += in[(size_t)n * FI + k] * ws_s[k * 32 + j];
#pragma unroll
  for (int k = 0; k < FI; k++) a += hn[(size_t)n * FI + k] * wn_s[k * 32 + j];
  out[(size_t)n * 32 + j] = fmaxf(a, 0.f);
}

// ---------------------------------------------------------------------------
// Final MLP: out = relu([gat,x2] @ f1 + b1) @ f2 + b2   (thread per node)
// ---------------------------------------------------------------------------
__global__ __attribute__((amdgpu_waves_per_eu(4, 4))) __launch_bounds__(256)
void final_kernel(const float* __restrict__ gat,
                  const float* __restrict__ x2,
                  const float* __restrict__ f1w,
                  const float* __restrict__ f1b,
                  const float* __restrict__ f2w,
                  const float* __restrict__ f2b,
                  float* __restrict__ out) {
  __shared__ float w1_s[64 * 16];
  __shared__ float b1_s[16];
  __shared__ float w2_s[16];
  for (int idx = threadIdx.x; idx < 1024; idx += 256) w1_s[idx] = f1w[idx];
  if (threadIdx.x < 16) {
    b1_s[threadIdx.x] = f1b[threadIdx.x];
    w2_s[threadIdx.x] = f2w[threadIdx.x];
  }
  __syncthreads();
  const int n = blockIdx.x * 256 + threadIdx.x;
  float z[64];
#pragma unroll
  for (int k = 0; k < 32; k += 4) {
    float4 a = *(const float4*)&gat[(size_t)n * 32 + k];
    z[k] = a.x; z[k + 1] = a.y; z[k + 2] = a.z; z[k + 3] = a.w;
    float4 b = *(const float4*)&x2[(size_t)n * 32 + k];
    z[32 + k] = b.x; z[32 + k + 1] = b.y; z[32 + k + 2] = b.z; z[32 + k + 3] = b.w;
  }
  float o = f2b[0];
#pragma unroll
  for (int j = 0; j < 16; j++) {
    float a = b1_s[j];
#pragma unroll
    for (int k = 0; k < 64; k++) a += z[k] * w1_s[k * 16 + j];
    o += fmaxf(a, 0.f) * w2_s[j];
  }
  out[n] = o;
}

extern "C" void kernel_launch(void* const* d_in, const int* in_sizes, int n_in,
                              void* d_out, int out_size, void* d_ws, size_t ws_size,
                              hipStream_t stream) {
  const int N = NNODES;
  const float* feat = (const float*)d_in[0];
  const int* src = (const int*)d_in[1];
  const float* g0_ws = (const float*)d_in[2];
  const float* g0_bs = (const float*)d_in[3];
  const float* g0_wd = (const float*)d_in[4];
  const float* g0_bd = (const float*)d_in[5];
  const float* g0_attn = (const float*)d_in[6];
  const float* g0_bias = (const float*)d_in[7];
  const float* l0_w = (const float*)d_in[8];
  const float* l0_b = (const float*)d_in[9];
  const float* g1_ws = (const float*)d_in[10];
  const float* g1_bs = (const float*)d_in[11];
  const float* g1_wd = (const float*)d_in[12];
  const float* g1_bd = (const float*)d_in[13];
  const float* g1_attn = (const float*)d_in[14];
  const float* g1_bias = (const float*)d_in[15];
  const float* l1_w = (const float*)d_in[16];
  const float* l1_b = (const float*)d_in[17];
  const float* g2_ws = (const float*)d_in[18];
  const float* g2_bs = (const float*)d_in[19];
  const float* g2_wd = (const float*)d_in[20];
  const float* g2_bd = (const float*)d_in[21];
  const float* g2_attn = (const float*)d_in[22];
  const float* g2_bias = (const float*)d_in[23];
  const float* l2_w = (const float*)d_in[24];
  const float* l2_b = (const float*)d_in[25];
  const float* s1_wih = (const float*)d_in[26];
  const float* s1_whh = (const float*)d_in[27];
  const float* s1_b = (const float*)d_in[28];
  const float* s1_wself = (const float*)d_in[29];
  const float* s1_wneigh = (const float*)d_in[30];
  const float* s1_bias = (const float*)d_in[31];
  const float* s2_wih = (const float*)d_in[32];
  const float* s2_whh = (const float*)d_in[33];
  const float* s2_b = (const float*)d_in[34];
  const float* s2_wself = (const float*)d_in[35];
  const float* s2_wneigh = (const float*)d_in[36];
  const float* s2_bias = (const float*)d_in[37];
  const float* f1_w = (const float*)d_in[38];
  const float* f1_b = (const float*)d_in[39];
  const float* f2_w = (const float*)d_in[40];
  const float* f2_b = (const float*)d_in[41];

  float* A = (float*)d_ws;                // N*128
  float* B = A + (size_t)N * 128;
  float* C = B + (size_t)N * 128;
  float* D = C + (size_t)N * 128;
  float* E = D + (size_t)N * 128;         // total 84 MB

  // ---- GAT layer 0 (fi=5, H=4): fs->A fd->B lin->C ----
  fc3_kernel<5, 128><<<dim3(N / 32, 2, 3), 256, 0, stream>>>(
      feat, g0_ws, g0_bs, A, g0_wd, g0_bd, B, l0_w, l0_b, C);
  gat_kernel<4, true><<<N / 4, 256, 0, stream>>>(A, B, C, src, g0_attn, g0_bias, D);  // D = h1

  // ---- GAT layer 1 (fi=128, H=4) ----
  fc3_kernel<128, 128><<<dim3(N / 32, 2, 3), 256, 0, stream>>>(
      D, g1_ws, g1_bs, A, g1_wd, g1_bd, B, l1_w, l1_b, C);
  gat_kernel<4, true><<<N / 4, 256, 0, stream>>>(A, B, C, src, g1_attn, g1_bias, E);  // E = h2

  // ---- GAT layer 2 (fi=128, H=1) ----
  fc3_kernel<128, 32><<<dim3(N / 32, 1, 3), 256, 0, stream>>>(
      E, g2_ws, g2_bs, A, g2_wd, g2_bd, B, l2_w, l2_b, C);
  gat_kernel<1, false><<<N / 16, 256, 0, stream>>>(A, B, C, src, g2_attn, g2_bias, D);  // D = gat [N,32]

  // ---- SAGE layer 1 ----
  fw1_kernel<<<N / 256, 256, 0, stream>>>(feat, s1_wih, s1_b, E);  // E = FW1 [N,20]
  lstm1s_kernel<<<N / 256, 256, 0, stream>>>(E, src, s1_whh, feat, s1_wself,
                                             s1_wneigh, s1_bias, C);  // C = x1 [N,32]

  // ---- SAGE layer 2 ----
  fct_kernel<32, 128><<<dim3(N / 32, 2), 256, 0, stream>>>(C, s2_wih, s2_b, A);  // A = XW2
  lstm2_mfma_kernel<<<N / 64, 256, 0, stream>>>(A, src, s2_whh, E);  // E = hn2 [N,32]
  sage_out_kernel<32><<<N / 8, 256, 0, stream>>>(C, E, s2_wself, s2_wneigh,
                                                 s2_bias, B);  // B = x2 [N,32]

  // ---- Final MLP ----
  final_kernel<<<N / 256, 256, 0, stream>>>(D, B, f1_w, f1_b, f2_w, f2_b, (float*)d_out);
}

// Round 9
// 437.199 us; speedup vs baseline: 1.4461x; 1.0989x over previous
//
#include <hip/hip_runtime.h>
#include <hip/hip_bf16.h>

#define NNODES 32768
#define DEG 16

__device__ __forceinline__ float sigmoidf_(float x) { return 1.f / (1.f + __expf(-x)); }
__device__ __forceinline__ float tanhf_(float x) { return 1.f - 2.f / (__expf(2.f * x) + 1.f); }

typedef __attribute__((ext_vector_type(8))) short bf16x8;
typedef __attribute__((ext_vector_type(4))) float f32x4;

__device__ __forceinline__ unsigned short f2bf_(float x) {
  __hip_bfloat16 b = __float2bfloat16(x);
  union { __hip_bfloat16 b; unsigned short u; } cv;
  cv.b = b;
  return cv.u;
}
__device__ __forceinline__ float bf2f_(unsigned short u) {
  union { unsigned short u; __hip_bfloat16 b; } cv;
  cv.u = u;
  return __bfloat162float(cv.b);
}
// split 8 fp32 into hi/lo bf16 fragments (combined error ~2^-17 relative)
__device__ __forceinline__ void pack_hilo_(const float* v, bf16x8& hi, bf16x8& lo) {
#pragma unroll
  for (int j = 0; j < 8; j++) {
    unsigned short h = f2bf_(v[j]);
    float resid = v[j] - bf2f_(h);
    hi[j] = (short)h;
    lo[j] = (short)f2bf_(resid);
  }
}

// ---------------------------------------------------------------------------
// Weight repack for MFMA FCs: fp32 W -> fragment-ordered bf16 hi/lo.
// Packed idx p: j=p&7, lane=(p>>3)&63, rest=p>>9, ks=rest%KS, f=rest/KS;
// n=lane&15, q=lane>>4; element = W[k=32ks+8q+j][fo=16f+n] (or W[fo][k] if
// TRANS). hi block at base+p, lo at base+FI*FO+p.
// blockIdx.x = matrix id (7 matrices, one dispatch).
// ---------------------------------------------------------------------------
__global__ __launch_bounds__(256) void repack_w_kernel(
    const float* __restrict__ g1ws, const float* __restrict__ g1wd,
    const float* __restrict__ l1w, const float* __restrict__ g2ws,
    const float* __restrict__ g2wd, const float* __restrict__ l2w,
    const float* __restrict__ s2wih, short* __restrict__ out) {
  const int mid = blockIdx.x;
  const float* W;
  int FI, FO, TRANS;
  size_t base;
  if (mid == 0)      { W = g1ws;  FI = 128; FO = 128; TRANS = 0; base = 0; }
  else if (mid == 1) { W = g1wd;  FI = 128; FO = 128; TRANS = 0; base = 32768; }
  else if (mid == 2) { W = l1w;   FI = 128; FO = 128; TRANS = 0; base = 65536; }
  else if (mid == 3) { W = g2ws;  FI = 128; FO = 32;  TRANS = 0; base = 98304; }
  else if (mid == 4) { W = g2wd;  FI = 128; FO = 32;  TRANS = 0; base = 98304 + 8192; }
  else if (mid == 5) { W = l2w;   FI = 128; FO = 32;  TRANS = 0; base = 98304 + 16384; }
  else               { W = s2wih; FI = 32;  FO = 128; TRANS = 1; base = 122880; }
  const int KS = FI / 32;
  const int total = FI * FO;
  for (int p = threadIdx.x; p < total; p += 256) {
    int j = p & 7, lane = (p >> 3) & 63, rest = p >> 9;
    int ks = rest % KS, f = rest / KS;
    int n = lane & 15, q = lane >> 4;
    int k = 32 * ks + 8 * q + j, fo = 16 * f + n;
    float v = TRANS ? W[(size_t)fo * FI + k] : W[(size_t)k * FO + fo];
    unsigned short hi = f2bf_(v);
    float resid = v - bf2f_(hi);
    out[base + p] = (short)hi;
    out[base + total + p] = (short)f2bf_(resid);
  }
}

// ---------------------------------------------------------------------------
// MFMA FC: out_z[N][FO] = in[N][FI] @ W_z + b_z, fp32 via bf16 hi/lo
// (3 MFMAs per K-tile; dropped lo*lo ~2^-18 rel — absmax 0.0 in R8 lstm2).
// Wave = 16 nodes; block = 4 waves = 64 nodes; A-frags (input rows) in regs,
// B-frags streamed b128 from packed W (L2-resident). C/D layout (m89):
// col=lane&15=fo-col, row=4q+r=node -> stores are 64B-coalesced per r.
// LDS pad caps occupancy at 4 blocks/CU so the RA targets a 128-reg budget
// (R2..R8 lesson: with tiny LDS it targets 8 waves/64 regs and spills).
// R8 evidence for the replaced fc3<128,128>: 88us, VALUBusy 76%, MfmaUtil 0,
// 30% occupancy — vector-ALU path at ~36 TF vs ~12-16us memory floor.
// ---------------------------------------------------------------------------
template <int KS, int FOT, int NZ>  // FI=32*KS, FO=16*FOT
__global__ __launch_bounds__(256) __attribute__((amdgpu_waves_per_eu(1, 4)))
void mfma_fc_kernel(const float* __restrict__ in, const short* __restrict__ Wp,
                    const float* __restrict__ B0, const float* __restrict__ B1,
                    const float* __restrict__ B2, float* __restrict__ O0,
                    float* __restrict__ O1, float* __restrict__ O2) {
  constexpr int FI = 32 * KS;
  constexpr int FO = 16 * FOT;
  __shared__ float lds_pad[9600];  // 38.4 KB -> 4 blocks/CU cap
  if ((const void*)in == nullptr) lds_pad[0] = 1.f;  // keep pad allocated
  const int tid = threadIdx.x;
  const int wid = tid >> 6;
  const int lane = tid & 63;
  const int q = lane >> 4, n = lane & 15;
  const int n0 = blockIdx.x * 64 + wid * 16;  // wave's node base
  // A fragments: A[m=n][k=32ks+8q+j] = in[n0+n][...], hi/lo split
  bf16x8 Ahi[KS], Alo[KS];
#pragma unroll
  for (int ks = 0; ks < KS; ks++) {
    float av[8];
    *(float4*)&av[0] = *(const float4*)&in[(size_t)(n0 + n) * FI + 32 * ks + 8 * q];
    *(float4*)&av[4] = *(const float4*)&in[(size_t)(n0 + n) * FI + 32 * ks + 8 * q + 4];
    pack_hilo_(av, Ahi[ks], Alo[ks]);
  }
#pragma unroll
  for (int z = 0; z < NZ; z++) {
    const short* wz = Wp + (size_t)z * FI * FO * 2;
    const float* bz = (z == 0) ? B0 : (z == 1) ? B1 : B2;
    float* oz = (z == 0) ? O0 : (z == 1) ? O1 : O2;
#pragma unroll
    for (int f = 0; f < FOT; f++) {
      float bv = bz[16 * f + n];
      f32x4 acc = {bv, bv, bv, bv};
#pragma unroll
      for (int ks = 0; ks < KS; ks++) {
        bf16x8 Bhi = *(const bf16x8*)&wz[((size_t)(f * KS + ks) * 64 + lane) * 8];
        bf16x8 Blo = *(const bf16x8*)&wz[(size_t)FI * FO + ((size_t)(f * KS + ks) * 64 + lane) * 8];
        acc = __builtin_amdgcn_mfma_f32_16x16x32_bf16(Ahi[ks], Bhi, acc, 0, 0, 0);
        acc = __builtin_amdgcn_mfma_f32_16x16x32_bf16(Alo[ks], Bhi, acc, 0, 0, 0);
        acc = __builtin_amdgcn_mfma_f32_16x16x32_bf16(Ahi[ks], Blo, acc, 0, 0, 0);
      }
#pragma unroll
      for (int r = 0; r < 4; r++)
        oz[(size_t)(n0 + 4 * q + r) * FO + 16 * f + n] = acc[r];
    }
  }
}

// ---------------------------------------------------------------------------
// Fused triple FC, vector-ALU path (kept for layer 0, FI=5).
// ---------------------------------------------------------------------------
template <int FI, int FO>
__global__ __launch_bounds__(256) void fc3_kernel(
    const float* __restrict__ in,
    const float* __restrict__ W0, const float* __restrict__ B0, float* __restrict__ O0,
    const float* __restrict__ W1, const float* __restrict__ B1, float* __restrict__ O1,
    const float* __restrict__ W2, const float* __restrict__ B2, float* __restrict__ O2) {
  constexpr int ROWS = 32;
  constexpr int FOT = (FO < 64) ? FO : 64;
  constexpr int NJ = FOT;
  constexpr int RSL = 256 / NJ;
  constexpr int R = ROWS / RSL;
  constexpr int PFI = (FI + 4) & ~3;
  __shared__ float w_s[FI * FOT];
  __shared__ float in_s[ROWS * PFI];
  __shared__ float b_s[FOT];
  const float* W = (blockIdx.z == 0) ? W0 : (blockIdx.z == 1) ? W1 : W2;
  const float* bias = (blockIdx.z == 0) ? B0 : (blockIdx.z == 1) ? B1 : B2;
  float* out = (blockIdx.z == 0) ? O0 : (blockIdx.z == 1) ? O1 : O2;
  const int t = threadIdx.x;
  const int rowBase = blockIdx.x * ROWS;
  const int colBase = blockIdx.y * FOT;
  for (int idx = t; idx < FI * FOT; idx += 256) {
    int k = idx / FOT, jj = idx - k * FOT;
    w_s[idx] = W[(size_t)k * FO + colBase + jj];
  }
  if (t < FOT) b_s[t] = bias[colBase + t];
  for (int idx = t; idx < ROWS * FI; idx += 256) {
    int r = idx / FI, k = idx - r * FI;
    in_s[r * PFI + k] = in[(size_t)(rowBase + r) * FI + k];
  }
  __syncthreads();
  const int jj = t % NJ;
  const int rslot = t / NJ;
  float acc[R];
#pragma unroll
  for (int r = 0; r < R; r++) acc[r] = b_s[jj];
  constexpr int K4 = FI / 4;
#pragma unroll
  for (int k4 = 0; k4 < K4; k4++) {
    float wv0 = w_s[(4 * k4 + 0) * FOT + jj];
    float wv1 = w_s[(4 * k4 + 1) * FOT + jj];
    float wv2 = w_s[(4 * k4 + 2) * FOT + jj];
    float wv3 = w_s[(4 * k4 + 3) * FOT + jj];
#pragma unroll
    for (int r = 0; r < R; r++) {
      float4 ip = *(const float4*)&in_s[(rslot * R + r) * PFI + 4 * k4];
      acc[r] += ip.x * wv0 + ip.y * wv1 + ip.z * wv2 + ip.w * wv3;
    }
  }
#pragma unroll
  for (int k = 4 * K4; k < FI; k++) {
    float wv = w_s[k * FOT + jj];
#pragma unroll
    for (int r = 0; r < R; r++) acc[r] += in_s[(rslot * R + r) * PFI + k] * wv;
  }
#pragma unroll
  for (int r = 0; r < R; r++)
    out[(size_t)(rowBase + rslot * R + r) * FO + colBase + jj] = acc[r];
}

// ---------------------------------------------------------------------------
// GATv2 attention + epilogue (unchanged).
// ---------------------------------------------------------------------------
template <int H, bool ELU>
__global__ __launch_bounds__(256) void gat_kernel(const float* __restrict__ fs,
                                                  const float* __restrict__ fd,
                                                  const float* __restrict__ lin,
                                                  const int* __restrict__ src,
                                                  const float* __restrict__ attn,
                                                  const float* __restrict__ bias,
                                                  float* __restrict__ out) {
  constexpr int F = H * 32;
  const int lane = threadIdx.x & 63;
  const int wave = threadIdx.x >> 6;
  const int G = lane >> 4, li = lane & 15;
  int node, f0;
  if (H == 4) {
    node = blockIdx.x * 4 + wave;
    f0 = 2 * lane;
  } else {
    node = blockIdx.x * 16 + wave * 4 + G;
    f0 = 2 * li;
  }
  const int srcv = src[(size_t)node * DEG + li];
  const float2 fdv = *(const float2*)&fd[(size_t)node * F + f0];
  const float a0 = attn[f0];
  const float a1 = attn[f0 + 1];
  float m = -1e30f, s = 0.f, acc0 = 0.f, acc1 = 0.f;
  int sd = __shfl(srcv, (lane & 48), 64);
  float2 fsv = *(const float2*)&fs[(size_t)sd * F + f0];
#pragma unroll
  for (int d = 0; d < DEG; d++) {
    float2 cur = fsv;
    if (d < DEG - 1) {
      int sn = __shfl(srcv, (lane & 48) | (d + 1), 64);
      fsv = *(const float2*)&fs[(size_t)sn * F + f0];
    }
    float e0 = cur.x + fdv.x; e0 = (e0 > 0.f) ? e0 : 0.2f * e0;
    float e1 = cur.y + fdv.y; e1 = (e1 > 0.f) ? e1 : 0.2f * e1;
    float p = e0 * a0 + e1 * a1;
    p += __shfl_xor(p, 1, 64);
    p += __shfl_xor(p, 2, 64);
    p += __shfl_xor(p, 4, 64);
    p += __shfl_xor(p, 8, 64);
    float nm = fmaxf(m, p);
    float ex = __expf(p - nm);
    float sc = __expf(m - nm);
    s = s * sc + ex;
    acc0 = acc0 * sc + ex * cur.x;
    acc1 = acc1 * sc + ex * cur.y;
    m = nm;
  }
  float inv = 1.f / s;
  float2 lv = *(const float2*)&lin[(size_t)node * F + f0];
  float o0 = acc0 * inv + lv.x + bias[f0];
  float o1 = acc1 * inv + lv.y + bias[f0 + 1];
  if (ELU) {
    o0 = (o0 > 0.f) ? o0 : __expf(o0) - 1.f;
    o1 = (o1 > 0.f) ? o1 : __expf(o1) - 1.f;
  }
  *(float2*)&out[(size_t)node * F + f0] = make_float2(o0, o1);
}

// ---------------------------------------------------------------------------
// SAGE-1 input projection: FW[n][20] = feat[n][5] @ wih.T + b   (thread/node)
// ---------------------------------------------------------------------------
__global__ __launch_bounds__(256) void fw1_kernel(const float* __restrict__ feat,
                                                  const float* __restrict__ wih,
                                                  const float* __restrict__ b,
                                                  float* __restrict__ out) {
  __shared__ float w_s[100];
  __shared__ float b_s[20];
  if (threadIdx.x < 100) w_s[threadIdx.x] = wih[threadIdx.x];
  if (threadIdx.x < 20) b_s[threadIdx.x] = b[threadIdx.x];
  __syncthreads();
  const int n = blockIdx.x * 256 + threadIdx.x;
  float f[5];
#pragma unroll
  for (int k = 0; k < 5; k++) f[k] = feat[(size_t)n * 5 + k];
#pragma unroll
  for (int j = 0; j < 20; j++) {
    float a = b_s[j];
#pragma unroll
    for (int k = 0; k < 5; k++) a += f[k] * w_s[j * 5 + k];
    out[(size_t)n * 20 + j] = a;
  }
}

// ---------------------------------------------------------------------------
// SAGE-1: LSTM (hidden=5, thread/node) + fused output projection (unchanged).
// ---------------------------------------------------------------------------
__global__ __attribute__((amdgpu_waves_per_eu(1, 4))) __launch_bounds__(256)
void lstm1s_kernel(const float* __restrict__ FW, const int* __restrict__ src,
                   const float* __restrict__ whh, const float* __restrict__ feat,
                   const float* __restrict__ wself, const float* __restrict__ wneigh,
                   const float* __restrict__ bias, float* __restrict__ x1out) {
  __shared__ float w_s[100];   // whh [20][5]
  __shared__ float ws_s[160];  // wself [5][32]
  __shared__ float wn_s[160];  // wneigh [5][32]
  __shared__ float b_s[32];
  if (threadIdx.x < 100) w_s[threadIdx.x] = whh[threadIdx.x];
  if (threadIdx.x < 160) {
    ws_s[threadIdx.x] = wself[threadIdx.x];
    wn_s[threadIdx.x] = wneigh[threadIdx.x];
  }
  if (threadIdx.x < 32) b_s[threadIdx.x] = bias[threadIdx.x];
  __syncthreads();
  const int n = blockIdx.x * 256 + threadIdx.x;
  const int* sp = src + (size_t)n * DEG;
  float f[5];
#pragma unroll
  for (int k = 0; k < 5; k++) f[k] = feat[(size_t)n * 5 + k];
  float h[5] = {0, 0, 0, 0, 0}, c[5] = {0, 0, 0, 0, 0};
  int sd = sp[0];
  float4 p0 = *(const float4*)&FW[(size_t)sd * 20 + 0];
  float4 p1 = *(const float4*)&FW[(size_t)sd * 20 + 4];
  float4 p2 = *(const float4*)&FW[(size_t)sd * 20 + 8];
  float4 p3 = *(const float4*)&FW[(size_t)sd * 20 + 12];
  float4 p4 = *(const float4*)&FW[(size_t)sd * 20 + 16];
  for (int d = 0; d < DEG; d++) {
    float g[20];
    g[0] = p0.x; g[1] = p0.y; g[2] = p0.z; g[3] = p0.w;
    g[4] = p1.x; g[5] = p1.y; g[6] = p1.z; g[7] = p1.w;
    g[8] = p2.x; g[9] = p2.y; g[10] = p2.z; g[11] = p2.w;
    g[12] = p3.x; g[13] = p3.y; g[14] = p3.z; g[15] = p3.w;
    g[16] = p4.x; g[17] = p4.y; g[18] = p4.z; g[19] = p4.w;
    if (d < DEG - 1) {
      int sn = sp[d + 1];
      p0 = *(const float4*)&FW[(size_t)sn * 20 + 0];
      p1 = *(const float4*)&FW[(size_t)sn * 20 + 4];
      p2 = *(const float4*)&FW[(size_t)sn * 20 + 8];
      p3 = *(const float4*)&FW[(size_t)sn * 20 + 12];
      p4 = *(const float4*)&FW[(size_t)sn * 20 + 16];
    }
#pragma unroll
    for (int j = 0; j < 20; j++) {
#pragma unroll
      for (int k = 0; k < 5; k++) g[j] += h[k] * w_s[j * 5 + k];
    }
#pragma unroll
    for (int k = 0; k < 5; k++) {
      float iv = sigmoidf_(g[k]);
      float fv = sigmoidf_(g[5 + k]);
      float gv = tanhf_(g[10 + k]);
      float ov = sigmoidf_(g[15 + k]);
      c[k] = fv * c[k] + iv * gv;
      h[k] = ov * tanhf_(c[k]);
    }
  }
#pragma unroll
  for (int j = 0; j < 32; j++) {
    float a = b_s[j];
#pragma unroll
    for (int k = 0; k < 5; k++) a += f[k] * ws_s[k * 32 + j] + h[k] * wn_s[k * 32 + j];
    x1out[(size_t)n * 32 + j] = fmaxf(a, 0.f);
  }
}

// ---------------------------------------------------------------------------
// SAGE-2 LSTM v5 (MFMA): ONE WAVE per 16 nodes, zero barriers (unchanged, R8).
// ---------------------------------------------------------------------------
__global__ __launch_bounds__(256) __attribute__((amdgpu_waves_per_eu(1, 2)))
void lstm2_mfma_kernel(const float* __restrict__ XW, const int* __restrict__ src,
                       const float* __restrict__ whh, float* __restrict__ hn_out) {
  __shared__ float h_lds_all[4 * 16 * 36];
  __shared__ int src_lds_all[4 * 256];
  __shared__ float lds_pad[15000];  // occupancy cap: ~73 KB total -> 2 blocks/CU
  if ((const void*)XW == nullptr) lds_pad[0] = 1.f;  // keep pad allocated
  const int tid = threadIdx.x;
  const int wid = tid >> 6;
  const int lane = tid & 63;
  const int q = lane >> 4;   // quad
  const int n = lane & 15;   // node within group / fragment col
  const int n0 = (blockIdx.x * 4 + wid) * 16;
  float* h_lds = &h_lds_all[wid * 16 * 36];
  int* src_lds = &src_lds_all[wid * 256];

  {
    int4 sv = *(const int4*)&src[(size_t)(n0 + (lane >> 2)) * DEG + 4 * (lane & 3)];
    src_lds[(4 * (lane & 3) + 0) * 16 + (lane >> 2)] = sv.x;
    src_lds[(4 * (lane & 3) + 1) * 16 + (lane >> 2)] = sv.y;
    src_lds[(4 * (lane & 3) + 2) * 16 + (lane >> 2)] = sv.z;
    src_lds[(4 * (lane & 3) + 3) * 16 + (lane >> 2)] = sv.w;
  }

  bf16x8 Whi[8], Wlo[8];
#pragma unroll
  for (int gt = 0; gt < 8; gt++) {
    float wv[8];
    *(float4*)&wv[0] = *(const float4*)&whh[(size_t)(16 * gt + n) * 32 + 8 * q];
    *(float4*)&wv[4] = *(const float4*)&whh[(size_t)(16 * gt + n) * 32 + 8 * q + 4];
    pack_hilo_(wv, Whi[gt], Wlo[gt]);
  }

  bf16x8 Bhi, Blo;
#pragma unroll
  for (int j = 0; j < 8; j++) { Bhi[j] = 0; Blo[j] = 0; }
  float cst[8];
#pragma unroll
  for (int i = 0; i < 8; i++) cst[i] = 0.f;

  float4 tc[8], tn[8];
  {
    int s0 = src_lds[0 * 16 + n];
    const float* gb = XW + (size_t)s0 * 128;
#pragma unroll
    for (int i = 0; i < 8; i++) tc[i] = *(const float4*)&gb[16 * i + 4 * q];
  }

  float hv[8];
#pragma unroll
  for (int d = 0; d < DEG; d++) {
    f32x4 D[4][2];
#pragma unroll
    for (int p = 0; p < 4; p++) {
#pragma unroll
      for (int hh = 0; hh < 2; hh++) {
        int gt = p * 2 + hh;
        f32x4 acc = {0.f, 0.f, 0.f, 0.f};
        acc = __builtin_amdgcn_mfma_f32_16x16x32_bf16(Whi[gt], Bhi, acc, 0, 0, 0);
        acc = __builtin_amdgcn_mfma_f32_16x16x32_bf16(Wlo[gt], Bhi, acc, 0, 0, 0);
        acc = __builtin_amdgcn_mfma_f32_16x16x32_bf16(Whi[gt], Blo, acc, 0, 0, 0);
        D[p][hh] = acc;
      }
    }
    if (d < DEG - 1) {
      int s = src_lds[(d + 1) * 16 + n];
      const float* gb = XW + (size_t)s * 128;
#pragma unroll
      for (int i = 0; i < 8; i++) tn[i] = *(const float4*)&gb[16 * i + 4 * q];
    }
#pragma unroll
    for (int hh = 0; hh < 2; hh++) {
      float4 xi = tc[0 + hh];
      float4 xf = tc[2 + hh];
      float4 xg = tc[4 + hh];
      float4 xo = tc[6 + hh];
#pragma unroll
      for (int r = 0; r < 4; r++) {
        float xiv = (r == 0) ? xi.x : (r == 1) ? xi.y : (r == 2) ? xi.z : xi.w;
        float xfv = (r == 0) ? xf.x : (r == 1) ? xf.y : (r == 2) ? xf.z : xf.w;
        float xgv = (r == 0) ? xg.x : (r == 1) ? xg.y : (r == 2) ? xg.z : xg.w;
        float xov = (r == 0) ? xo.x : (r == 1) ? xo.y : (r == 2) ? xo.z : xo.w;
        int ci = hh * 4 + r;
        float iv = sigmoidf_(D[0][hh][r] + xiv);
        float fv = sigmoidf_(D[1][hh][r] + xfv);
        float gv = tanhf_(D[2][hh][r] + xgv);
        float ov = sigmoidf_(D[3][hh][r] + xov);
        cst[ci] = fv * cst[ci] + iv * gv;
        hv[ci] = ov * tanhf_(cst[ci]);
      }
    }
    if (d < DEG - 1) {
      *(float4*)&h_lds[n * 36 + 0 + 4 * q] = make_float4(hv[0], hv[1], hv[2], hv[3]);
      *(float4*)&h_lds[n * 36 + 16 + 4 * q] = make_float4(hv[4], hv[5], hv[6], hv[7]);
      float hb[8];
      *(float4*)&hb[0] = *(const float4*)&h_lds[n * 36 + 8 * q];
      *(float4*)&hb[4] = *(const float4*)&h_lds[n * 36 + 8 * q + 4];
      pack_hilo_(hb, Bhi, Blo);
#pragma unroll
      for (int i = 0; i < 8; i++) tc[i] = tn[i];
    }
  }
  *(float4*)&hn_out[(size_t)(n0 + n) * 32 + 0 + 4 * q] = make_float4(hv[0], hv[1], hv[2], hv[3]);
  *(float4*)&hn_out[(size_t)(n0 + n) * 32 + 16 + 4 * q] = make_float4(hv[4], hv[5], hv[6], hv[7]);
}

// ---------------------------------------------------------------------------
// SAGE output: out = relu(in @ wself + hn @ wneigh + bias), FO=32
// ---------------------------------------------------------------------------
template <int FI>
__global__ __launch_bounds__(256) void sage_out_kernel(const float* __restrict__ in,
                                                       const float* __restrict__ hn,
                                                       const float* __restrict__ wself,
                                                       const float* __restrict__ wneigh,
                                                       const float* __restrict__ bias,
                                                       float* __restrict__ out) {
  __shared__ float ws_s[FI * 32];
  __shared__ float wn_s[FI * 32];
  __shared__ float b_s[32];
  for (int idx = threadIdx.x; idx < FI * 32; idx += 256) {
    ws_s[idx] = wself[idx];
    wn_s[idx] = wneigh[idx];
  }
  if (threadIdx.x < 32) b_s[threadIdx.x] = bias[threadIdx.x];
  __syncthreads();
  const int n = blockIdx.x * 8 + (threadIdx.x >> 5);
  const int j = threadIdx.x & 31;
  float a = b_s[j];
#pragma unroll
  for (int k = 0; k < FI; k++) a += in[(size_t)n * FI + k] * ws_s[k * 32 + j];
#pragma unroll
  for (int k = 0; k < FI; k++) a += hn[(size_t)n * FI + k] * wn_s[k * 32 + j];
  out[(size_t)n * 32 + j] = fmaxf(a, 0.f);
}

// ---------------------------------------------------------------------------
// Final MLP: out = relu([gat,x2] @ f1 + b1) @ f2 + b2   (thread per node)
// ---------------------------------------------------------------------------
__global__ __attribute__((amdgpu_waves_per_eu(4, 4))) __launch_bounds__(256)
void final_kernel(const float* __restrict__ gat,
                  const float* __restrict__ x2,
                  const float* __restrict__ f1w,
                  const float* __restrict__ f1b,
                  const float* __restrict__ f2w,
                  const float* __restrict__ f2b,
                  float* __restrict__ out) {
  __shared__ float w1_s[64 * 16];
  __shared__ float b1_s[16];
  __shared__ float w2_s[16];
  for (int idx = threadIdx.x; idx < 1024; idx += 256) w1_s[idx] = f1w[idx];
  if (threadIdx.x < 16) {
    b1_s[threadIdx.x] = f1b[threadIdx.x];
    w2_s[threadIdx.x] = f2w[threadIdx.x];
  }
  __syncthreads();
  const int n = blockIdx.x * 256 + threadIdx.x;
  float z[64];
#pragma unroll
  for (int k = 0; k < 32; k += 4) {
    float4 a = *(const float4*)&gat[(size_t)n * 32 + k];
    z[k] = a.x; z[k + 1] = a.y; z[k + 2] = a.z; z[k + 3] = a.w;
    float4 b = *(const float4*)&x2[(size_t)n * 32 + k];
    z[32 + k] = b.x; z[32 + k + 1] = b.y; z[32 + k + 2] = b.z; z[32 + k + 3] = b.w;
  }
  float o = f2b[0];
#pragma unroll
  for (int j = 0; j < 16; j++) {
    float a = b1_s[j];
#pragma unroll
    for (int k = 0; k < 64; k++) a += z[k] * w1_s[k * 16 + j];
    o += fmaxf(a, 0.f) * w2_s[j];
  }
  out[n] = o;
}

extern "C" void kernel_launch(void* const* d_in, const int* in_sizes, int n_in,
                              void* d_out, int out_size, void* d_ws, size_t ws_size,
                              hipStream_t stream) {
  const int N = NNODES;
  const float* feat = (const float*)d_in[0];
  const int* src = (const int*)d_in[1];
  const float* g0_ws = (const float*)d_in[2];
  const float* g0_bs = (const float*)d_in[3];
  const float* g0_wd = (const float*)d_in[4];
  const float* g0_bd = (const float*)d_in[5];
  const float* g0_attn = (const float*)d_in[6];
  const float* g0_bias = (const float*)d_in[7];
  const float* l0_w = (const float*)d_in[8];
  const float* l0_b = (const float*)d_in[9];
  const float* g1_ws = (const float*)d_in[10];
  const float* g1_bs = (const float*)d_in[11];
  const float* g1_wd = (const float*)d_in[12];
  const float* g1_bd = (const float*)d_in[13];
  const float* g1_attn = (const float*)d_in[14];
  const float* g1_bias = (const float*)d_in[15];
  const float* l1_w = (const float*)d_in[16];
  const float* l1_b = (const float*)d_in[17];
  const float* g2_ws = (const float*)d_in[18];
  const float* g2_bs = (const float*)d_in[19];
  const float* g2_wd = (const float*)d_in[20];
  const float* g2_bd = (const float*)d_in[21];
  const float* g2_attn = (const float*)d_in[22];
  const float* g2_bias = (const float*)d_in[23];
  const float* l2_w = (const float*)d_in[24];
  const float* l2_b = (const float*)d_in[25];
  const float* s1_wih = (const float*)d_in[26];
  const float* s1_whh = (const float*)d_in[27];
  const float* s1_b = (const float*)d_in[28];
  const float* s1_wself = (const float*)d_in[29];
  const float* s1_wneigh = (const float*)d_in[30];
  const float* s1_bias = (const float*)d_in[31];
  const float* s2_wih = (const float*)d_in[32];
  const float* s2_whh = (const float*)d_in[33];
  const float* s2_b = (const float*)d_in[34];
  const float* s2_wself = (const float*)d_in[35];
  const float* s2_wneigh = (const float*)d_in[36];
  const float* s2_bias = (const float*)d_in[37];
  const float* f1_w = (const float*)d_in[38];
  const float* f1_b = (const float*)d_in[39];
  const float* f2_w = (const float*)d_in[40];
  const float* f2_b = (const float*)d_in[41];

  float* A = (float*)d_ws;                // N*128
  float* B = A + (size_t)N * 128;
  float* C = B + (size_t)N * 128;
  float* D = C + (size_t)N * 128;
  float* E = D + (size_t)N * 128;         // A..E = 84 MB
  short* Wp = (short*)(A + (size_t)5 * N * 128);  // packed bf16 weights, 256 KB

  // ---- weight repack for MFMA FCs (one dispatch; graph-stable) ----
  repack_w_kernel<<<7, 256, 0, stream>>>(g1_ws, g1_wd, l1_w, g2_ws, g2_wd,
                                         l2_w, s2_wih, Wp);

  // ---- GAT layer 0 (fi=5, H=4): fs->A fd->B lin->C ----
  fc3_kernel<5, 128><<<dim3(N / 32, 2, 3), 256, 0, stream>>>(
      feat, g0_ws, g0_bs, A, g0_wd, g0_bd, B, l0_w, l0_b, C);
  gat_kernel<4, true><<<N / 4, 256, 0, stream>>>(A, B, C, src, g0_attn, g0_bias, D);  // D = h1

  // ---- GAT layer 1 (fi=128, H=4), MFMA ----
  mfma_fc_kernel<4, 8, 3><<<N / 64, 256, 0, stream>>>(
      D, Wp, g1_bs, g1_bd, l1_b, A, B, C);
  gat_kernel<4, true><<<N / 4, 256, 0, stream>>>(A, B, C, src, g1_attn, g1_bias, E);  // E = h2

  // ---- GAT layer 2 (fi=128, H=1), MFMA ----
  mfma_fc_kernel<4, 2, 3><<<N / 64, 256, 0, stream>>>(
      E, Wp + 98304, g2_bs, g2_bd, l2_b, A, B, C);
  gat_kernel<1, false><<<N / 16, 256, 0, stream>>>(A, B, C, src, g2_attn, g2_bias, D);  // D = gat [N,32]

  // ---- SAGE layer 1 ----
  fw1_kernel<<<N / 256, 256, 0, stream>>>(feat, s1_wih, s1_b, E);  // E = FW1 [N,20]
  lstm1s_kernel<<<N / 256, 256, 0, stream>>>(E, src, s1_whh, feat, s1_wself,
                                             s1_wneigh, s1_bias, C);  // C = x1 [N,32]

  // ---- SAGE layer 2 ----
  mfma_fc_kernel<1, 8, 1><<<N / 64, 256, 0, stream>>>(
      C, Wp + 122880, s2_b, nullptr, nullptr, A, nullptr, nullptr);  // A = XW2
  lstm2_mfma_kernel<<<N / 64, 256, 0, stream>>>(A, src, s2_whh, E);  // E = hn2 [N,32]
  sage_out_kernel<32><<<N / 8, 256, 0, stream>>>(C, E, s2_wself, s2_wneigh,
                                                 s2_bias, B);  // B = x2 [N,32]

  // ---- Final MLP ----
  final_kernel<<<N / 256, 256, 0, stream>>>(D, B, f1_w, f1_b, f2_w, f2_b, (float*)d_out);
}

// Round 12
// 427.049 us; speedup vs baseline: 1.4805x; 1.0238x over previous
//
#include <hip/hip_runtime.h>
#include <hip/hip_bf16.h>

#define NNODES 32768
#define DEG 16

__device__ __forceinline__ float sigmoidf_(float x) { return 1.f / (1.f + __expf(-x)); }
__device__ __forceinline__ float tanhf_(float x) { return 1.f - 2.f / (__expf(2.f * x) + 1.f); }

typedef __attribute__((ext_vector_type(8))) short bf16x8;
typedef __attribute__((ext_vector_type(4))) float f32x4;

__device__ __forceinline__ unsigned short f2bf_(float x) {
  __hip_bfloat16 b = __float2bfloat16(x);
  union { __hip_bfloat16 b; unsigned short u; } cv;
  cv.b = b;
  return cv.u;
}
__device__ __forceinline__ float bf2f_(unsigned short u) {
  union { unsigned short u; __hip_bfloat16 b; } cv;
  cv.u = u;
  return __bfloat162float(cv.b);
}
__device__ __forceinline__ void pack_hilo_(const float* v, bf16x8& hi, bf16x8& lo) {
#pragma unroll
  for (int j = 0; j < 8; j++) {
    unsigned short h = f2bf_(v[j]);
    float resid = v[j] - bf2f_(h);
    hi[j] = (short)h;
    lo[j] = (short)f2bf_(resid);
  }
}

// Packed-weight offsets (shorts); hi block then lo block per matrix.
#define WP_G1    0        // 3 x (128x128): stride 32768
#define WP_G2    98304    // 3 x (128x32):  stride 8192
#define WP_S2WIH 122880   // 32x128 (transposed use)
#define WP_TOTAL 131072

// ---------------------------------------------------------------------------
// Startup mega-kernel: [0,6144) = fc3 layer0; [6144,6151) = weight repack.
// KEPT from R10/R11 (mechanical grid-flattening of R9's passing kernels).
// R12 bisect: lstm2/lstm1s reverted to R9-exact; if this round STILL fails,
// the bug is provably in this fusion or gat1_fw1 and R13 reverts them.
// ---------------------------------------------------------------------------
__global__ __launch_bounds__(256) void startup_kernel(
    const float* __restrict__ feat,
    const float* __restrict__ W0, const float* __restrict__ B0,
    const float* __restrict__ W1, const float* __restrict__ B1,
    const float* __restrict__ W2, const float* __restrict__ B2,
    float* __restrict__ O0, float* __restrict__ O1, float* __restrict__ O2,
    const float* __restrict__ g1ws, const float* __restrict__ g1wd,
    const float* __restrict__ l1w, const float* __restrict__ g2ws,
    const float* __restrict__ g2wd, const float* __restrict__ l2w,
    const float* __restrict__ s2wih, short* __restrict__ Wp) {
  __shared__ float w_s[5 * 64];
  __shared__ float in_s[32 * 8];
  __shared__ float b_s[64];
  const int bid = blockIdx.x;
  const int t = threadIdx.x;
  if (bid < 6144) {
    const int bz = bid >> 11, rem = bid & 2047, by = rem >> 10, bx = rem & 1023;
    const float* W = (bz == 0) ? W0 : (bz == 1) ? W1 : W2;
    const float* bias = (bz == 0) ? B0 : (bz == 1) ? B1 : B2;
    float* out = (bz == 0) ? O0 : (bz == 1) ? O1 : O2;
    const int rowBase = bx * 32;
    const int colBase = by * 64;
    for (int idx = t; idx < 5 * 64; idx += 256) {
      int k = idx >> 6, jj = idx & 63;
      w_s[idx] = W[(size_t)k * 128 + colBase + jj];
    }
    if (t < 64) b_s[t] = bias[colBase + t];
    for (int idx = t; idx < 32 * 5; idx += 256) {
      int r = idx / 5, k = idx - r * 5;
      in_s[r * 8 + k] = feat[(size_t)(rowBase + r) * 5 + k];
    }
    __syncthreads();
    const int jj = t & 63;
    const int rslot = t >> 6;
    float acc[8];
#pragma unroll
    for (int r = 0; r < 8; r++) acc[r] = b_s[jj];
    {
      float wv0 = w_s[0 * 64 + jj], wv1 = w_s[1 * 64 + jj];
      float wv2 = w_s[2 * 64 + jj], wv3 = w_s[3 * 64 + jj];
#pragma unroll
      for (int r = 0; r < 8; r++) {
        float4 ip = *(const float4*)&in_s[(rslot * 8 + r) * 8];
        acc[r] += ip.x * wv0 + ip.y * wv1 + ip.z * wv2 + ip.w * wv3;
      }
      float wv4 = w_s[4 * 64 + jj];
#pragma unroll
      for (int r = 0; r < 8; r++) acc[r] += in_s[(rslot * 8 + r) * 8 + 4] * wv4;
    }
#pragma unroll
    for (int r = 0; r < 8; r++)
      out[(size_t)(rowBase + rslot * 8 + r) * 128 + colBase + jj] = acc[r];
  } else {
    const int mid = bid - 6144;
    const float* W;
    int FI, FO, TRANS;
    size_t base;
    if (mid == 0)      { W = g1ws;  FI = 128; FO = 128; TRANS = 0; base = WP_G1; }
    else if (mid == 1) { W = g1wd;  FI = 128; FO = 128; TRANS = 0; base = WP_G1 + 32768; }
    else if (mid == 2) { W = l1w;   FI = 128; FO = 128; TRANS = 0; base = WP_G1 + 65536; }
    else if (mid == 3) { W = g2ws;  FI = 128; FO = 32;  TRANS = 0; base = WP_G2; }
    else if (mid == 4) { W = g2wd;  FI = 128; FO = 32;  TRANS = 0; base = WP_G2 + 8192; }
    else if (mid == 5) { W = l2w;   FI = 128; FO = 32;  TRANS = 0; base = WP_G2 + 16384; }
    else               { W = s2wih; FI = 32;  FO = 128; TRANS = 1; base = WP_S2WIH; }
    const int KS = FI / 32;
    const int total = FI * FO;
    for (int p = t; p < total; p += 256) {
      int j = p & 7, lane = (p >> 3) & 63, rest = p >> 9;
      int ks = rest % KS, f = rest / KS;
      int n = lane & 15, q = lane >> 4;
      int k = 32 * ks + 8 * q + j, fo = 16 * f + n;
      float v = TRANS ? W[(size_t)fo * FI + k] : W[(size_t)k * FO + fo];
      unsigned short hi = f2bf_(v);
      float resid = v - bf2f_(hi);
      Wp[base + p] = (short)hi;
      Wp[base + total + p] = (short)f2bf_(resid);
    }
  }
}

// ---------------------------------------------------------------------------
// MFMA FC (unchanged from R9).
// ---------------------------------------------------------------------------
template <int KS, int FOT, int NZ>  // FI=32*KS, FO=16*FOT
__global__ __launch_bounds__(256) __attribute__((amdgpu_waves_per_eu(1, 4)))
void mfma_fc_kernel(const float* __restrict__ in, const short* __restrict__ Wp,
                    const float* __restrict__ B0, const float* __restrict__ B1,
                    const float* __restrict__ B2, float* __restrict__ O0,
                    float* __restrict__ O1, float* __restrict__ O2) {
  constexpr int FI = 32 * KS;
  constexpr int FO = 16 * FOT;
  __shared__ float lds_pad[9600];
  if ((const void*)in == nullptr) lds_pad[0] = 1.f;
  const int tid = threadIdx.x;
  const int wid = tid >> 6;
  const int lane = tid & 63;
  const int q = lane >> 4, n = lane & 15;
  const int n0 = blockIdx.x * 64 + wid * 16;
  bf16x8 Ahi[KS], Alo[KS];
#pragma unroll
  for (int ks = 0; ks < KS; ks++) {
    float av[8];
    *(float4*)&av[0] = *(const float4*)&in[(size_t)(n0 + n) * FI + 32 * ks + 8 * q];
    *(float4*)&av[4] = *(const float4*)&in[(size_t)(n0 + n) * FI + 32 * ks + 8 * q + 4];
    pack_hilo_(av, Ahi[ks], Alo[ks]);
  }
#pragma unroll
  for (int z = 0; z < NZ; z++) {
    const short* wz = Wp + (size_t)z * FI * FO * 2;
    const float* bz = (z == 0) ? B0 : (z == 1) ? B1 : B2;
    float* oz = (z == 0) ? O0 : (z == 1) ? O1 : O2;
#pragma unroll
    for (int f = 0; f < FOT; f++) {
      float bv = bz[16 * f + n];
      f32x4 acc = {bv, bv, bv, bv};
#pragma unroll
      for (int ks = 0; ks < KS; ks++) {
        bf16x8 Bhi = *(const bf16x8*)&wz[((size_t)(f * KS + ks) * 64 + lane) * 8];
        bf16x8 Blo = *(const bf16x8*)&wz[(size_t)FI * FO + ((size_t)(f * KS + ks) * 64 + lane) * 8];
        acc = __builtin_amdgcn_mfma_f32_16x16x32_bf16(Ahi[ks], Bhi, acc, 0, 0, 0);
        acc = __builtin_amdgcn_mfma_f32_16x16x32_bf16(Alo[ks], Bhi, acc, 0, 0, 0);
        acc = __builtin_amdgcn_mfma_f32_16x16x32_bf16(Ahi[ks], Blo, acc, 0, 0, 0);
      }
#pragma unroll
      for (int r = 0; r < 4; r++)
        oz[(size_t)(n0 + 4 * q + r) * FO + 16 * f + n] = acc[r];
    }
  }
}

// ---------------------------------------------------------------------------
// GATv2 H=4 (unchanged).
// ---------------------------------------------------------------------------
__global__ __launch_bounds__(256) void gat4_kernel(const float* __restrict__ fs,
                                                   const float* __restrict__ fd,
                                                   const float* __restrict__ lin,
                                                   const int* __restrict__ src,
                                                   const float* __restrict__ attn,
                                                   const float* __restrict__ bias,
                                                   float* __restrict__ out) {
  constexpr int F = 128;
  const int lane = threadIdx.x & 63;
  const int wave = threadIdx.x >> 6;
  const int li = lane & 15;
  const int node = blockIdx.x * 4 + wave;
  const int f0 = 2 * lane;
  const int srcv = src[(size_t)node * DEG + li];
  const float2 fdv = *(const float2*)&fd[(size_t)node * F + f0];
  const float a0 = attn[f0];
  const float a1 = attn[f0 + 1];
  float m = -1e30f, s = 0.f, acc0 = 0.f, acc1 = 0.f;
  int sd = __shfl(srcv, (lane & 48), 64);
  float2 fsv = *(const float2*)&fs[(size_t)sd * F + f0];
#pragma unroll
  for (int d = 0; d < DEG; d++) {
    float2 cur = fsv;
    if (d < DEG - 1) {
      int sn = __shfl(srcv, (lane & 48) | (d + 1), 64);
      fsv = *(const float2*)&fs[(size_t)sn * F + f0];
    }
    float e0 = cur.x + fdv.x; e0 = (e0 > 0.f) ? e0 : 0.2f * e0;
    float e1 = cur.y + fdv.y; e1 = (e1 > 0.f) ? e1 : 0.2f * e1;
    float p = e0 * a0 + e1 * a1;
    p += __shfl_xor(p, 1, 64);
    p += __shfl_xor(p, 2, 64);
    p += __shfl_xor(p, 4, 64);
    p += __shfl_xor(p, 8, 64);
    float nm = fmaxf(m, p);
    float ex = __expf(p - nm);
    float sc = __expf(m - nm);
    s = s * sc + ex;
    acc0 = acc0 * sc + ex * cur.x;
    acc1 = acc1 * sc + ex * cur.y;
    m = nm;
  }
  float inv = 1.f / s;
  float2 lv = *(const float2*)&lin[(size_t)node * F + f0];
  float o0 = acc0 * inv + lv.x + bias[f0];
  float o1 = acc1 * inv + lv.y + bias[f0 + 1];
  o0 = (o0 > 0.f) ? o0 : __expf(o0) - 1.f;
  o1 = (o1 > 0.f) ? o1 : __expf(o1) - 1.f;
  *(float2*)&out[(size_t)node * F + f0] = make_float2(o0, o1);
}

// ---------------------------------------------------------------------------
// GATv2 H=1 (no ELU) + fused fw1 (kept from R10/R11 — mechanical fusion).
// ---------------------------------------------------------------------------
__global__ __launch_bounds__(256) void gat1_fw1_kernel(
    const float* __restrict__ fs, const float* __restrict__ fd,
    const float* __restrict__ lin, const int* __restrict__ src,
    const float* __restrict__ attn, const float* __restrict__ bias,
    float* __restrict__ out, const float* __restrict__ feat,
    const float* __restrict__ wih, const float* __restrict__ wb,
    float* __restrict__ fwout) {
  __shared__ float w_s[100];
  __shared__ float b_s[20];
  if (blockIdx.x < 2048) {
    constexpr int F = 32;
    const int lane = threadIdx.x & 63;
    const int wave = threadIdx.x >> 6;
    const int G = lane >> 4, li = lane & 15;
    const int node = blockIdx.x * 16 + wave * 4 + G;
    const int f0 = 2 * li;
    const int srcv = src[(size_t)node * DEG + li];
    const float2 fdv = *(const float2*)&fd[(size_t)node * F + f0];
    const float a0 = attn[f0];
    const float a1 = attn[f0 + 1];
    float m = -1e30f, s = 0.f, acc0 = 0.f, acc1 = 0.f;
    int sd = __shfl(srcv, (lane & 48), 64);
    float2 fsv = *(const float2*)&fs[(size_t)sd * F + f0];
#pragma unroll
    for (int d = 0; d < DEG; d++) {
      float2 cur = fsv;
      if (d < DEG - 1) {
        int sn = __shfl(srcv, (lane & 48) | (d + 1), 64);
        fsv = *(const float2*)&fs[(size_t)sn * F + f0];
      }
      float e0 = cur.x + fdv.x; e0 = (e0 > 0.f) ? e0 : 0.2f * e0;
      float e1 = cur.y + fdv.y; e1 = (e1 > 0.f) ? e1 : 0.2f * e1;
      float p = e0 * a0 + e1 * a1;
      p += __shfl_xor(p, 1, 64);
      p += __shfl_xor(p, 2, 64);
      p += __shfl_xor(p, 4, 64);
      p += __shfl_xor(p, 8, 64);
      float nm = fmaxf(m, p);
      float ex = __expf(p - nm);
      float sc = __expf(m - nm);
      s = s * sc + ex;
      acc0 = acc0 * sc + ex * cur.x;
      acc1 = acc1 * sc + ex * cur.y;
      m = nm;
    }
    float inv = 1.f / s;
    float2 lv = *(const float2*)&lin[(size_t)node * F + f0];
    float o0 = acc0 * inv + lv.x + bias[f0];
    float o1 = acc1 * inv + lv.y + bias[f0 + 1];
    *(float2*)&out[(size_t)node * F + f0] = make_float2(o0, o1);
  } else {
    if (threadIdx.x < 100) w_s[threadIdx.x] = wih[threadIdx.x];
    if (threadIdx.x < 20) b_s[threadIdx.x] = wb[threadIdx.x];
    __syncthreads();
    const int n = (blockIdx.x - 2048) * 256 + threadIdx.x;
    float f[5];
#pragma unroll
    for (int k = 0; k < 5; k++) f[k] = feat[(size_t)n * 5 + k];
#pragma unroll
    for (int j = 0; j < 20; j++) {
      float a = b_s[j];
#pragma unroll
      for (int k = 0; k < 5; k++) a += f[k] * w_s[j * 5 + k];
      fwout[(size_t)n * 20 + j] = a;
    }
  }
}

// ---------------------------------------------------------------------------
// SAGE-1: LSTM + fused projection — R9 VERBATIM (block 256, grid N/256).
// ---------------------------------------------------------------------------
__global__ __attribute__((amdgpu_waves_per_eu(1, 4))) __launch_bounds__(256)
void lstm1s_kernel(const float* __restrict__ FW, const int* __restrict__ src,
                   const float* __restrict__ whh, const float* __restrict__ feat,
                   const float* __restrict__ wself, const float* __restrict__ wneigh,
                   const float* __restrict__ bias, float* __restrict__ x1out) {
  __shared__ float w_s[100];   // whh [20][5]
  __shared__ float ws_s[160];  // wself [5][32]
  __shared__ float wn_s[160];  // wneigh [5][32]
  __shared__ float b_s[32];
  if (threadIdx.x < 100) w_s[threadIdx.x] = whh[threadIdx.x];
  if (threadIdx.x < 160) {
    ws_s[threadIdx.x] = wself[threadIdx.x];
    wn_s[threadIdx.x] = wneigh[threadIdx.x];
  }
  if (threadIdx.x < 32) b_s[threadIdx.x] = bias[threadIdx.x];
  __syncthreads();
  const int n = blockIdx.x * 256 + threadIdx.x;
  const int* sp = src + (size_t)n * DEG;
  float f[5];
#pragma unroll
  for (int k = 0; k < 5; k++) f[k] = feat[(size_t)n * 5 + k];
  float h[5] = {0, 0, 0, 0, 0}, c[5] = {0, 0, 0, 0, 0};
  int sd = sp[0];
  float4 p0 = *(const float4*)&FW[(size_t)sd * 20 + 0];
  float4 p1 = *(const float4*)&FW[(size_t)sd * 20 + 4];
  float4 p2 = *(const float4*)&FW[(size_t)sd * 20 + 8];
  float4 p3 = *(const float4*)&FW[(size_t)sd * 20 + 12];
  float4 p4 = *(const float4*)&FW[(size_t)sd * 20 + 16];
  for (int d = 0; d < DEG; d++) {
    float g[20];
    g[0] = p0.x; g[1] = p0.y; g[2] = p0.z; g[3] = p0.w;
    g[4] = p1.x; g[5] = p1.y; g[6] = p1.z; g[7] = p1.w;
    g[8] = p2.x; g[9] = p2.y; g[10] = p2.z; g[11] = p2.w;
    g[12] = p3.x; g[13] = p3.y; g[14] = p3.z; g[15] = p3.w;
    g[16] = p4.x; g[17] = p4.y; g[18] = p4.z; g[19] = p4.w;
    if (d < DEG - 1) {
      int sn = sp[d + 1];
      p0 = *(const float4*)&FW[(size_t)sn * 20 + 0];
      p1 = *(const float4*)&FW[(size_t)sn * 20 + 4];
      p2 = *(const float4*)&FW[(size_t)sn * 20 + 8];
      p3 = *(const float4*)&FW[(size_t)sn * 20 + 12];
      p4 = *(const float4*)&FW[(size_t)sn * 20 + 16];
    }
#pragma unroll
    for (int j = 0; j < 20; j++) {
#pragma unroll
      for (int k = 0; k < 5; k++) g[j] += h[k] * w_s[j * 5 + k];
    }
#pragma unroll
    for (int k = 0; k < 5; k++) {
      float iv = sigmoidf_(g[k]);
      float fv = sigmoidf_(g[5 + k]);
      float gv = tanhf_(g[10 + k]);
      float ov = sigmoidf_(g[15 + k]);
      c[k] = fv * c[k] + iv * gv;
      h[k] = ov * tanhf_(c[k]);
    }
  }
#pragma unroll
  for (int j = 0; j < 32; j++) {
    float a = b_s[j];
#pragma unroll
    for (int k = 0; k < 5; k++) a += f[k] * ws_s[k * 32 + j] + h[k] * wn_s[k * 32 + j];
    x1out[(size_t)n * 32 + j] = fmaxf(a, 0.f);
  }
}

// ---------------------------------------------------------------------------
// SAGE-2 LSTM (MFMA) — R9 VERBATIM (1-deep prefetch). R12 bisect reverts the
// R10/R11 2-deep prefetch rewrite (highest-complexity surviving diff).
// ---------------------------------------------------------------------------
__global__ __launch_bounds__(256) __attribute__((amdgpu_waves_per_eu(1, 2)))
void lstm2_mfma_kernel(const float* __restrict__ XW, const int* __restrict__ src,
                       const float* __restrict__ whh, float* __restrict__ hn_out) {
  __shared__ float h_lds_all[4 * 16 * 36];
  __shared__ int src_lds_all[4 * 256];
  __shared__ float lds_pad[15000];  // occupancy cap: ~73 KB total -> 2 blocks/CU
  if ((const void*)XW == nullptr) lds_pad[0] = 1.f;  // keep pad allocated
  const int tid = threadIdx.x;
  const int wid = tid >> 6;
  const int lane = tid & 63;
  const int q = lane >> 4;   // quad
  const int n = lane & 15;   // node within group / fragment col
  const int n0 = (blockIdx.x * 4 + wid) * 16;
  float* h_lds = &h_lds_all[wid * 16 * 36];
  int* src_lds = &src_lds_all[wid * 256];

  {
    int4 sv = *(const int4*)&src[(size_t)(n0 + (lane >> 2)) * DEG + 4 * (lane & 3)];
    src_lds[(4 * (lane & 3) + 0) * 16 + (lane >> 2)] = sv.x;
    src_lds[(4 * (lane & 3) + 1) * 16 + (lane >> 2)] = sv.y;
    src_lds[(4 * (lane & 3) + 2) * 16 + (lane >> 2)] = sv.z;
    src_lds[(4 * (lane & 3) + 3) * 16 + (lane >> 2)] = sv.w;
  }

  bf16x8 Whi[8], Wlo[8];
#pragma unroll
  for (int gt = 0; gt < 8; gt++) {
    float wv[8];
    *(float4*)&wv[0] = *(const float4*)&whh[(size_t)(16 * gt + n) * 32 + 8 * q];
    *(float4*)&wv[4] = *(const float4*)&whh[(size_t)(16 * gt + n) * 32 + 8 * q + 4];
    pack_hilo_(wv, Whi[gt], Wlo[gt]);
  }

  bf16x8 Bhi, Blo;
#pragma unroll
  for (int j = 0; j < 8; j++) { Bhi[j] = 0; Blo[j] = 0; }
  float cst[8];
#pragma unroll
  for (int i = 0; i < 8; i++) cst[i] = 0.f;

  float4 tc[8], tn[8];
  {
    int s0 = src_lds[0 * 16 + n];
    const float* gb = XW + (size_t)s0 * 128;
#pragma unroll
    for (int i = 0; i < 8; i++) tc[i] = *(const float4*)&gb[16 * i + 4 * q];
  }

  float hv[8];
#pragma unroll
  for (int d = 0; d < DEG; d++) {
    f32x4 D[4][2];
#pragma unroll
    for (int p = 0; p < 4; p++) {
#pragma unroll
      for (int hh = 0; hh < 2; hh++) {
        int gt = p * 2 + hh;
        f32x4 acc = {0.f, 0.f, 0.f, 0.f};
        acc = __builtin_amdgcn_mfma_f32_16x16x32_bf16(Whi[gt], Bhi, acc, 0, 0, 0);
        acc = __builtin_amdgcn_mfma_f32_16x16x32_bf16(Wlo[gt], Bhi, acc, 0, 0, 0);
        acc = __builtin_amdgcn_mfma_f32_16x16x32_bf16(Whi[gt], Blo, acc, 0, 0, 0);
        D[p][hh] = acc;
      }
    }
    if (d < DEG - 1) {
      int s = src_lds[(d + 1) * 16 + n];
      const float* gb = XW + (size_t)s * 128;
#pragma unroll
      for (int i = 0; i < 8; i++) tn[i] = *(const float4*)&gb[16 * i + 4 * q];
    }
#pragma unroll
    for (int hh = 0; hh < 2; hh++) {
      float4 xi = tc[0 + hh];
      float4 xf = tc[2 + hh];
      float4 xg = tc[4 + hh];
      float4 xo = tc[6 + hh];
#pragma unroll
      for (int r = 0; r < 4; r++) {
        float xiv = (r == 0) ? xi.x : (r == 1) ? xi.y : (r == 2) ? xi.z : xi.w;
        float xfv = (r == 0) ? xf.x : (r == 1) ? xf.y : (r == 2) ? xf.z : xf.w;
        float xgv = (r == 0) ? xg.x : (r == 1) ? xg.y : (r == 2) ? xg.z : xg.w;
        float xov = (r == 0) ? xo.x : (r == 1) ? xo.y : (r == 2) ? xo.z : xo.w;
        int ci = hh * 4 + r;
        float iv = sigmoidf_(D[0][hh][r] + xiv);
        float fv = sigmoidf_(D[1][hh][r] + xfv);
        float gv = tanhf_(D[2][hh][r] + xgv);
        float ov = sigmoidf_(D[3][hh][r] + xov);
        cst[ci] = fv * cst[ci] + iv * gv;
        hv[ci] = ov * tanhf_(cst[ci]);
      }
    }
    if (d < DEG - 1) {
      *(float4*)&h_lds[n * 36 + 0 + 4 * q] = make_float4(hv[0], hv[1], hv[2], hv[3]);
      *(float4*)&h_lds[n * 36 + 16 + 4 * q] = make_float4(hv[4], hv[5], hv[6], hv[7]);
      float hb[8];
      *(float4*)&hb[0] = *(const float4*)&h_lds[n * 36 + 8 * q];
      *(float4*)&hb[4] = *(const float4*)&h_lds[n * 36 + 8 * q + 4];
      pack_hilo_(hb, Bhi, Blo);
#pragma unroll
      for (int i = 0; i < 8; i++) tc[i] = tn[i];
    }
  }
  *(float4*)&hn_out[(size_t)(n0 + n) * 32 + 0 + 4 * q] = make_float4(hv[0], hv[1], hv[2], hv[3]);
  *(float4*)&hn_out[(size_t)(n0 + n) * 32 + 16 + 4 * q] = make_float4(hv[4], hv[5], hv[6], hv[7]);
}

// ---------------------------------------------------------------------------
// SAGE output (R9 fp32 kernel): out = relu(in@wself + hn@wneigh + b)
// ---------------------------------------------------------------------------
template <int FI>
__global__ __launch_bounds__(256) void sage_out_kernel(const float* __restrict__ in,
                                                       const float* __restrict__ hn,
                                                       const float* __restrict__ wself,
                                                       const float* __restrict__ wneigh,
                                                       const float* __restrict__ bias,
                                                       float* __restrict__ out) {
  __shared__ float ws_s[FI * 32];
  __shared__ float wn_s[FI * 32];
  __shared__ float b_s[32];
  for (int idx = threadIdx.x; idx < FI * 32; idx += 256) {
    ws_s[idx] = wself[idx];
    wn_s[idx] = wneigh[idx];
  }
  if (threadIdx.x < 32) b_s[threadIdx.x] = bias[threadIdx.x];
  __syncthreads();
  const int n = blockIdx.x * 8 + (threadIdx.x >> 5);
  const int j = threadIdx.x & 31;
  float a = b_s[j];
#pragma unroll
  for (int k = 0; k < FI; k++) a += in[(size_t)n * FI + k] * ws_s[k * 32 + j];
#pragma unroll
  for (int k = 0; k < FI; k++) a += hn[(size_t)n * FI + k] * wn_s[k * 32 + j];
  out[(size_t)n * 32 + j] = fmaxf(a, 0.f);
}

// ---------------------------------------------------------------------------
// Final MLP (unchanged).
// ---------------------------------------------------------------------------
__global__ __attribute__((amdgpu_waves_per_eu(4, 4))) __launch_bounds__(256)
void final_kernel(const float* __restrict__ gat,
                  const float* __restrict__ x2,
                  const float* __restrict__ f1w,
                  const float* __restrict__ f1b,
                  const float* __restrict__ f2w,
                  const float* __restrict__ f2b,
                  float* __restrict__ out) {
  __shared__ float w1_s[64 * 16];
  __shared__ float b1_s[16];
  __shared__ float w2_s[16];
  for (int idx = threadIdx.x; idx < 1024; idx += 256) w1_s[idx] = f1w[idx];
  if (threadIdx.x < 16) {
    b1_s[threadIdx.x] = f1b[threadIdx.x];
    w2_s[threadIdx.x] = f2w[threadIdx.x];
  }
  __syncthreads();
  const int n = blockIdx.x * 256 + threadIdx.x;
  float z[64];
#pragma unroll
  for (int k = 0; k < 32; k += 4) {
    float4 a = *(const float4*)&gat[(size_t)n * 32 + k];
    z[k] = a.x; z[k + 1] = a.y; z[k + 2] = a.z; z[k + 3] = a.w;
    float4 b = *(const float4*)&x2[(size_t)n * 32 + k];
    z[32 + k] = b.x; z[32 + k + 1] = b.y; z[32 + k + 2] = b.z; z[32 + k + 3] = b.w;
  }
  float o = f2b[0];
#pragma unroll
  for (int j = 0; j < 16; j++) {
    float a = b1_s[j];
#pragma unroll
    for (int k = 0; k < 64; k++) a += z[k] * w1_s[k * 16 + j];
    o += fmaxf(a, 0.f) * w2_s[j];
  }
  out[n] = o;
}

extern "C" void kernel_launch(void* const* d_in, const int* in_sizes, int n_in,
                              void* d_out, int out_size, void* d_ws, size_t ws_size,
                              hipStream_t stream) {
  const int N = NNODES;
  const float* feat = (const float*)d_in[0];
  const int* src = (const int*)d_in[1];
  const float* g0_ws = (const float*)d_in[2];
  const float* g0_bs = (const float*)d_in[3];
  const float* g0_wd = (const float*)d_in[4];
  const float* g0_bd = (const float*)d_in[5];
  const float* g0_attn = (const float*)d_in[6];
  const float* g0_bias = (const float*)d_in[7];
  const float* l0_w = (const float*)d_in[8];
  const float* l0_b = (const float*)d_in[9];
  const float* g1_ws = (const float*)d_in[10];
  const float* g1_bs = (const float*)d_in[11];
  const float* g1_wd = (const float*)d_in[12];
  const float* g1_bd = (const float*)d_in[13];
  const float* g1_attn = (const float*)d_in[14];
  const float* g1_bias = (const float*)d_in[15];
  const float* l1_w = (const float*)d_in[16];
  const float* l1_b = (const float*)d_in[17];
  const float* g2_ws = (const float*)d_in[18];
  const float* g2_bs = (const float*)d_in[19];
  const float* g2_wd = (const float*)d_in[20];
  const float* g2_bd = (const float*)d_in[21];
  const float* g2_attn = (const float*)d_in[22];
  const float* g2_bias = (const float*)d_in[23];
  const float* l2_w = (const float*)d_in[24];
  const float* l2_b = (const float*)d_in[25];
  const float* s1_wih = (const float*)d_in[26];
  const float* s1_whh = (const float*)d_in[27];
  const float* s1_b = (const float*)d_in[28];
  const float* s1_wself = (const float*)d_in[29];
  const float* s1_wneigh = (const float*)d_in[30];
  const float* s1_bias = (const float*)d_in[31];
  const float* s2_wih = (const float*)d_in[32];
  const float* s2_whh = (const float*)d_in[33];
  const float* s2_b = (const float*)d_in[34];
  const float* s2_wself = (const float*)d_in[35];
  const float* s2_wneigh = (const float*)d_in[36];
  const float* s2_bias = (const float*)d_in[37];
  const float* f1_w = (const float*)d_in[38];
  const float* f1_b = (const float*)d_in[39];
  const float* f2_w = (const float*)d_in[40];
  const float* f2_b = (const float*)d_in[41];

  float* A = (float*)d_ws;                // N*128
  float* B = A + (size_t)N * 128;
  float* C = B + (size_t)N * 128;
  float* D = C + (size_t)N * 128;
  float* E = D + (size_t)N * 128;         // A..E = 84 MB
  short* Wp = (short*)(A + (size_t)5 * N * 128);  // packed bf16 weights, 262 KB

  // 1. startup: fc3 layer0 (A=fs, B=fd, C=lin) + repack 7 weight matrices
  startup_kernel<<<6151, 256, 0, stream>>>(
      feat, g0_ws, g0_bs, g0_wd, g0_bd, l0_w, l0_b, A, B, C,
      g1_ws, g1_wd, l1_w, g2_ws, g2_wd, l2_w, s2_wih, Wp);
  // 2. GAT layer 0 -> D = h1
  gat4_kernel<<<N / 4, 256, 0, stream>>>(A, B, C, src, g0_attn, g0_bias, D);
  // 3. layer-1 FC trio (MFMA) -> A,B,C
  mfma_fc_kernel<4, 8, 3><<<N / 64, 256, 0, stream>>>(
      D, Wp + WP_G1, g1_bs, g1_bd, l1_b, A, B, C);
  // 4. GAT layer 1 -> E = h2
  gat4_kernel<<<N / 4, 256, 0, stream>>>(A, B, C, src, g1_attn, g1_bias, E);
  // 5. layer-2 FC trio (MFMA) -> A,B,C  (N x 32 each)
  mfma_fc_kernel<4, 2, 3><<<N / 64, 256, 0, stream>>>(
      E, Wp + WP_G2, g2_bs, g2_bd, l2_b, A, B, C);
  // 6. GAT layer 2 -> D = gat [N,32]; + fused fw1 -> E = FW1 [N,20]
  gat1_fw1_kernel<<<2048 + 128, 256, 0, stream>>>(
      A, B, C, src, g2_attn, g2_bias, D, feat, s1_wih, s1_b, E);
  // 7. SAGE-1 LSTM + projection -> C = x1 [N,32]   (R9-exact config)
  lstm1s_kernel<<<N / 256, 256, 0, stream>>>(E, src, s1_whh, feat, s1_wself,
                                             s1_wneigh, s1_bias, C);
  // 8. XW2 = x1 @ wih.T + b -> A [N,128]
  mfma_fc_kernel<1, 8, 1><<<N / 64, 256, 0, stream>>>(
      C, Wp + WP_S2WIH, s2_b, nullptr, nullptr, A, nullptr, nullptr);
  // 9. SAGE-2 LSTM -> E = hn2 [N,32]   (R9-exact kernel)
  lstm2_mfma_kernel<<<N / 64, 256, 0, stream>>>(A, src, s2_whh, E);
  // 10. sage_out (fp32, exact) -> B = x2 [N,32]
  sage_out_kernel<32><<<N / 8, 256, 0, stream>>>(C, E, s2_wself, s2_wneigh,
                                                 s2_bias, B);
  // 11. final MLP -> out
  final_kernel<<<N / 256, 256, 0, stream>>>(D, B, f1_w, f1_b, f2_w, f2_b, (float*)d_out);
}